// Round 10
// baseline (761.530 us; speedup 1.0000x reference)
//
#include <hip/hip_runtime.h>

typedef unsigned short u16;
typedef short s16x8 __attribute__((ext_vector_type(8)));
typedef float f32x4 __attribute__((ext_vector_type(4)));

#define S_TXTC 512
#define S_TOTC 2560
#define DM 3072
#define NH 24
#define HDM 128

__device__ __forceinline__ float b2f(u16 u){ unsigned int i = ((unsigned int)u)<<16; float f; __builtin_memcpy(&f,&i,4); return f; }
__device__ __forceinline__ u16 f2b(float f){ unsigned int i; __builtin_memcpy(&i,&f,4); unsigned int r = i + 0x7FFFu + ((i>>16)&1u); return (u16)(r>>16); }
__device__ __forceinline__ s16x8 pk8(float4 a, float4 b){
  s16x8 r;
  r[0]=(short)f2b(a.x); r[1]=(short)f2b(a.y); r[2]=(short)f2b(a.z); r[3]=(short)f2b(a.w);
  r[4]=(short)f2b(b.x); r[5]=(short)f2b(b.y); r[6]=(short)f2b(b.z); r[7]=(short)f2b(b.w);
  return r;
}
__device__ __forceinline__ void g2l16(const void* g, void* l){
  __builtin_amdgcn_global_load_lds((const __attribute__((address_space(1))) void*)g,
                                   (__attribute__((address_space(3))) void*)l, 16, 0, 0);
}

__global__ __launch_bounds__(256) void fillv(float* __restrict__ p, int n, float v){
  int i = blockIdx.x*256 + threadIdx.x;
  if (i < n) p[i] = v;
}

// ---------------- cast hidden+enc fp32 -> bf16 (contiguous dest) ----------------
__global__ __launch_bounds__(256) void cast2(const float* __restrict__ a, const float* __restrict__ b,
                                             u16* __restrict__ dst, int na8, int n8){
  int i = blockIdx.x*256 + threadIdx.x;
  if (i >= n8) return;
  const float* src = (i < na8)? a + (size_t)i*8 : b + (size_t)(i-na8)*8;
  float4 f0 = *(const float4*)src;
  float4 f1 = *(const float4*)(src+4);
  *(s16x8*)(dst + (size_t)i*8) = pk8(f0,f1);
}

// ---------------- concat 2x3 biases into 2x9216 fp32 ----------------
__global__ __launch_bounds__(256) void catbias2(const float* __restrict__ b0, const float* __restrict__ b1,
    const float* __restrict__ b2, const float* __restrict__ c0, const float* __restrict__ c1,
    const float* __restrict__ c2, float* __restrict__ dst){
  int i = blockIdx.x*256 + threadIdx.x;
  if (i >= 18432) return;
  int j = (i < 9216)? i : i - 9216;
  const float* s0 = (i<9216)? b0 : c0; const float* s1 = (i<9216)? b1 : c1; const float* s2 = (i<9216)? b2 : c2;
  dst[i] = (j<3072)? s0[j] : (j<6144? s1[j-3072] : s2[j-6144]);
}

// ---------------- transpose+cast up to 3 weights: Wt_bf16[n][k] = W_f32[k][n] ----------------
__global__ __launch_bounds__(256) void ktrans3(const float* __restrict__ W0, const float* __restrict__ W1,
    const float* __restrict__ W2, u16* __restrict__ D0, u16* __restrict__ D1, u16* __restrict__ D2){
  const float* W = (blockIdx.z==0)? W0 : ((blockIdx.z==1)? W1 : W2);
  u16* Wt = (blockIdx.z==0)? D0 : ((blockIdx.z==1)? D1 : D2);
  __shared__ __align__(16) u16 t[64*72];
  int nt = blockIdx.x*64, kt_ = blockIdx.y*64;
  int tid = threadIdx.x;
  #pragma unroll
  for (int i=0;i<2;i++){
    int q = tid + 256*i;
    int r = q>>3, c8 = (q&7)*8;
    float4 f0 = *(const float4*)(W + (size_t)(kt_+r)*DM + nt + c8);
    float4 f1 = *(const float4*)(W + (size_t)(kt_+r)*DM + nt + c8 + 4);
    *(s16x8*)&t[r*72 + c8] = pk8(f0,f1);
  }
  __syncthreads();
  #pragma unroll
  for (int i=0;i<2;i++){
    int q = tid + 256*i;
    int n = q>>3, k8 = (q&7)*8;
    s16x8 v;
    #pragma unroll
    for (int j=0;j<8;j++) v[j] = (short)t[(k8+j)*72 + n];
    *(s16x8*)(Wt + (size_t)(nt+n)*DM + kt_ + k8) = v;
  }
}

// ---------------- m97-style bf16 GEMM core ----------------
template<int OUT32>
__device__ __forceinline__ void gcore(u16* la, u16* lb,
    const u16* __restrict__ A, const u16* __restrict__ Bt,
    const float* __restrict__ bias, void* __restrict__ Cv,
    int ldc, int rb, int crb, int cb){
  const int K = DM;
  int tid = threadIdx.x, w = tid>>6, l = tid&63, g = l>>4, c16 = l&15;
  int wr = (w>>1)*64, wc = (w&1)*64;
  f32x4 acc[4][4] = {};
  const u16* aL = A  + (size_t)(rb + w*32 + (l>>2))*K + (l&3)*8;
  const u16* bL = Bt + (size_t)(cb + w*32 + (l>>2))*K + (l&3)*8;
  u16* laB = la + w*1024;
  u16* lbB = lb + w*1024;
  for (int ks=0; ks<K; ks+=32){
    g2l16(aL + ks,                laB);
    g2l16(aL + 16*(size_t)K + ks, laB + 512);
    g2l16(bL + ks,                lbB);
    g2l16(bL + 16*(size_t)K + ks, lbB + 512);
    __syncthreads();
    s16x8 af[4], bf[4];
    #pragma unroll
    for (int m=0;m<4;m++) af[m] = *(const s16x8*)&la[(wr + m*16 + c16)*32 + g*8];
    #pragma unroll
    for (int n=0;n<4;n++) bf[n] = *(const s16x8*)&lb[(wc + n*16 + c16)*32 + g*8];
    #pragma unroll
    for (int m=0;m<4;m++)
      #pragma unroll
      for (int n=0;n<4;n++)
        acc[m][n] = __builtin_amdgcn_mfma_f32_16x16x32_bf16(af[m], bf[n], acc[m][n], 0,0,0);
    __syncthreads();
  }
  #pragma unroll
  for (int n=0;n<4;n++){
    int col = cb + wc + n*16 + c16;
    float bv = bias[col];
    #pragma unroll
    for (int m=0;m<4;m++){
      int r0 = crb + wr + m*16 + g*4;
      #pragma unroll
      for (int r=0;r<4;r++){
        float oo = acc[m][n][r] + bv;
        if (OUT32) ((float*)Cv)[(size_t)(r0+r)*ldc + col] = oo;
        else       ((u16*)Cv)[(size_t)(r0+r)*ldc + col] = f2b(oo);
      }
    }
  }
}

__global__ __launch_bounds__(256) void qkv_gemm(const u16* __restrict__ A, const u16* __restrict__ Bt,
                                                const float* __restrict__ bias, u16* __restrict__ C){
  __shared__ __align__(16) u16 la[4096];
  __shared__ __align__(16) u16 lb[4096];
  gcore<0>(la, lb, A, Bt, bias, C, 3*DM, blockIdx.x*128, blockIdx.x*128, blockIdx.y*128);
}

__global__ __launch_bounds__(256) void out_gemm(const u16* __restrict__ hsb,
    const u16* __restrict__ woT, const u16* __restrict__ woaT,
    const float* __restrict__ bo, const float* __restrict__ boa, float* __restrict__ out){
  __shared__ __align__(16) u16 la[4096];
  __shared__ __align__(16) u16 lb[4096];
  int bx = blockIdx.x;
  bool txt = (bx < 4);
  int rb = bx*128;
  const u16* Bt = txt? woaT : woT;
  const float* bias = txt? boa : bo;
  float* dst = txt? out + (size_t)2048*DM : out;
  int crb = txt? rb : rb - 512;
  gcore<1>(la, lb, hsb, Bt, bias, dst, DM, rb, crb, blockIdx.y*128);
}

// ---------------- fused epilogues: blocks [0,30720) = qk RMSNorm+RoPE; [30720,31680) = v transpose ----------------
__global__ __launch_bounds__(256) void epi_fused(
    const u16* __restrict__ qkvI, const u16* __restrict__ qkvT,
    const float* __restrict__ nqw, const float* __restrict__ nkw,
    const float* __restrict__ naq, const float* __restrict__ nak,
    const float* __restrict__ fcos, const float* __restrict__ fsin,
    u16* __restrict__ qh, u16* __restrict__ kh, u16* __restrict__ vt){
  __shared__ __align__(16) u16 t[64*136];
  int blk = blockIdx.x;
  if (blk < 30720){
    int wid = blk*4 + (threadIdx.x>>6);
    int lane = threadIdx.x&63;
    int which = wid / (NH*S_TOTC);
    int rem = wid % (NH*S_TOTC);
    int h = rem / S_TOTC, tok = rem % S_TOTC;
    const u16* src = ((tok<S_TXTC)? qkvT + (size_t)tok*(3*DM) : qkvI + (size_t)(tok-S_TXTC)*(3*DM))
                     + which*DM + h*HDM;
    const float* nw = which? ((tok<S_TXTC)? nak : nkw) : ((tok<S_TXTC)? naq : nqw);
    int d = lane*2;
    unsigned int u = *(const unsigned int*)(src + d);
    float x0 = b2f((u16)(u&0xffffu)), x1 = b2f((u16)(u>>16));
    float ss = x0*x0 + x1*x1;
    #pragma unroll
    for (int m=1;m<64;m<<=1) ss += __shfl_xor(ss, m);
    float rr = rsqrtf(ss*(1.f/128.f) + 1e-6f);
    float y0 = x0*rr*nw[d];
    float y1 = x1*rr*nw[d+1];
    float2 cc = *(const float2*)(fcos + (size_t)tok*HDM + d);
    float2 sn = *(const float2*)(fsin + (size_t)tok*HDM + d);
    float sc = which? 1.0f : 0.08838834764831845f;   // fold 1/sqrt(HD) into Q
    float o0 = (y0*cc.x - y1*sn.x)*sc;
    float o1 = (y1*cc.y + y0*sn.y)*sc;
    u16* dst = (which? kh : qh) + ((size_t)h*S_TOTC + tok)*HDM + d;
    *(unsigned int*)dst = (unsigned int)f2b(o0) | ((unsigned int)f2b(o1)<<16);
  } else {
    int bv = blk - 30720;
    int h = bv % NH, tb = bv / NH;
    int tok0 = tb*64, tid = threadIdx.x;
    #pragma unroll
    for (int i=0;i<4;i++){
      int q = tid + 256*i;
      int tr = q>>4, c8 = (q&15)*8;
      int tok = tok0 + tr;
      const u16* src = ((tok<S_TXTC)? qkvT + (size_t)tok*(3*DM) : qkvI + (size_t)(tok-S_TXTC)*(3*DM))
                       + 2*DM + h*HDM;
      *(s16x8*)&t[tr*136 + c8] = *(const s16x8*)(src + c8);
    }
    __syncthreads();
    #pragma unroll
    for (int i=0;i<4;i++){
      int q = tid + 256*i;
      int d = q>>3, j8 = (q&7)*8;
      s16x8 v;
      #pragma unroll
      for (int j=0;j<8;j++) v[j] = (short)t[(j8+j)*136 + d];
      *(s16x8*)(vt + ((size_t)h*HDM + d)*S_TOTC + tok0 + j8) = v;
    }
  }
}

// ---------------- adapter projections: f32 (4x1024)@(1024x3072) -> bf16 [H][4][HD] ----------------
__global__ __launch_bounds__(256) void adapterk(const float* __restrict__ ad, const float* __restrict__ Wk,
        const float* __restrict__ Wv, u16* __restrict__ vdk, u16* __restrict__ vdv){
  int wid = blockIdx.x*4 + (threadIdx.x>>6);
  int lane = threadIdx.x&63;
  int tensor = wid / (4*DM);
  int rem = wid % (4*DM);
  int tok = rem / DM, col = rem % DM;
  const float* Wp = tensor? Wv : Wk;
  float s = 0.f;
  #pragma unroll
  for (int i=0;i<16;i++){
    int k = lane + 64*i;
    s += ad[tok*1024 + k] * Wp[(size_t)k*DM + col];
  }
  #pragma unroll
  for (int m=1;m<64;m<<=1) s += __shfl_xor(s, m);
  if (lane==0){
    int hh = col>>7, d = col&127;
    (tensor? vdv : vdk)[(hh*4+tok)*HDM + d] = f2b(s);
  }
}

// ---------------- fused MFMA flash attention: QBLK=128, 8 waves, KVBLK=64, reg-dbuf, defer-max ----------------
__global__ __launch_bounds__(512,4) void attnk(const u16* __restrict__ qh, const u16* __restrict__ kh,
    const u16* __restrict__ vt, const u16* __restrict__ vdk, const u16* __restrict__ vdv,
    const float* __restrict__ bscale, u16* __restrict__ hs){
  __shared__ __align__(16) u16 kts[64*136];    // [key][d] stride 136
  __shared__ __align__(16) u16 vts[128*72];    // [d][key] stride 72
  __shared__ __align__(16) u16 pwb[128*72];    // [q][key] stride 72
  int h = blockIdx.y, qb = blockIdx.x*128;
  int tid = threadIdx.x, w = tid>>6, l = tid&63, g = l>>4, c16 = l&15;
  int qrow = qb + w*16 + c16;
  s16x8 qf[4];
  #pragma unroll
  for (int kc=0;kc<4;kc++) qf[kc] = *(const s16x8*)(qh + ((size_t)h*S_TOTC + qrow)*HDM + kc*32 + g*8);
  f32x4 acc[8];
  #pragma unroll
  for (int dt=0;dt<8;dt++) acc[dt] = f32x4{0.f,0.f,0.f,0.f};
  float m_[4] = {-3e38f,-3e38f,-3e38f,-3e38f};
  float l_[4] = {0.f,0.f,0.f,0.f};
  const u16* khB = kh + (size_t)h*S_TOTC*HDM;
  const u16* vtB = vt + (size_t)h*HDM*S_TOTC;

  auto LOADT = [&](s16x8* kr, s16x8* vr, int kb){
    #pragma unroll
    for (int i=0;i<2;i++){
      int idx = tid + 512*i;
      kr[i] = *(const s16x8*)(khB + (size_t)(kb + (idx>>4))*HDM + (idx&15)*8);
      vr[i] = *(const s16x8*)(vtB + (size_t)(idx>>3)*S_TOTC + kb + (idx&7)*8);
    }
  };
  auto STORET = [&](s16x8* kr, s16x8* vr){
    #pragma unroll
    for (int i=0;i<2;i++){
      int idx = tid + 512*i;
      *(s16x8*)&kts[(idx>>4)*136 + (idx&15)*8] = kr[i];
      *(s16x8*)&vts[(idx>>3)*72 + (idx&7)*8] = vr[i];
    }
  };
  auto COMPUTE = [&](){
    f32x4 s[4];
    #pragma unroll
    for (int su=0;su<4;su++) s[su] = f32x4{0.f,0.f,0.f,0.f};
    __builtin_amdgcn_s_setprio(1);
    #pragma unroll
    for (int su=0;su<4;su++)
      #pragma unroll
      for (int kc=0;kc<4;kc++){
        s16x8 kf = *(const s16x8*)&kts[(su*16+c16)*136 + (kc*4+g)*8];
        s[su] = __builtin_amdgcn_mfma_f32_16x16x32_bf16(qf[kc], kf, s[su], 0,0,0);
      }
    __builtin_amdgcn_s_setprio(0);
    float tm[4];
    #pragma unroll
    for (int r=0;r<4;r++)
      tm[r] = fmaxf(fmaxf(s[0][r],s[1][r]), fmaxf(s[2][r],s[3][r]));
    #pragma unroll
    for (int m=1;m<16;m<<=1)
      #pragma unroll
      for (int r=0;r<4;r++) tm[r] = fmaxf(tm[r], __shfl_xor(tm[r], m));
    bool need = !__all(tm[0]<=m_[0]+8.f && tm[1]<=m_[1]+8.f && tm[2]<=m_[2]+8.f && tm[3]<=m_[3]+8.f);
    if (need){
      float corr[4];
      #pragma unroll
      for (int r=0;r<4;r++){
        float mn = fmaxf(m_[r], tm[r]);
        corr[r] = __expf(m_[r]-mn);
        m_[r] = mn;
        l_[r] *= corr[r];
      }
      #pragma unroll
      for (int dt=0;dt<8;dt++)
        #pragma unroll
        for (int r=0;r<4;r++) acc[dt][r] *= corr[r];
    }
    float rs[4];
    #pragma unroll
    for (int r=0;r<4;r++){
      rs[r] = 0.f;
      #pragma unroll
      for (int su=0;su<4;su++){ s[su][r] = __expf(s[su][r]-m_[r]); rs[r] += s[su][r]; }
    }
    #pragma unroll
    for (int m=1;m<16;m<<=1)
      #pragma unroll
      for (int r=0;r<4;r++) rs[r] += __shfl_xor(rs[r], m);
    #pragma unroll
    for (int r=0;r<4;r++) l_[r] += rs[r];
    #pragma unroll
    for (int su=0;su<4;su++)
      #pragma unroll
      for (int r=0;r<4;r++)
        pwb[(w*16 + g*4 + r)*72 + su*16 + c16] = f2b(s[su][r]);
    s16x8 pf0 = *(const s16x8*)&pwb[(w*16 + c16)*72 + g*8];
    s16x8 pf1 = *(const s16x8*)&pwb[(w*16 + c16)*72 + 32 + g*8];
    __builtin_amdgcn_s_setprio(1);
    #pragma unroll
    for (int dt=0;dt<8;dt++){
      s16x8 vf0 = *(const s16x8*)&vts[(dt*16 + c16)*72 + g*8];
      acc[dt] = __builtin_amdgcn_mfma_f32_16x16x32_bf16(pf0, vf0, acc[dt], 0,0,0);
      s16x8 vf1 = *(const s16x8*)&vts[(dt*16 + c16)*72 + 32 + g*8];
      acc[dt] = __builtin_amdgcn_mfma_f32_16x16x32_bf16(pf1, vf1, acc[dt], 0,0,0);
    }
    __builtin_amdgcn_s_setprio(0);
  };

  s16x8 ka[2], va[2], kb2[2], vb2[2];
  LOADT(ka, va, 0);
  for (int kb=0; kb<S_TOTC; kb+=128){
    STORET(ka, va);
    __syncthreads();
    LOADT(kb2, vb2, kb+64);
    COMPUTE();
    __syncthreads();
    STORET(kb2, vb2);
    __syncthreads();
    if (kb+128 < S_TOTC) LOADT(ka, va, kb+128);
    COMPUTE();
    __syncthreads();
  }

  // adapter cross-attention: stage 4 K rows / 4 V keys into kts/vts (stale rest is masked)
  if (tid < 64){
    int key = tid>>4, c8 = (tid&15)*8;
    *(s16x8*)&kts[key*136 + c8] = *(const s16x8*)(vdk + (h*4+key)*HDM + c8);
  } else if (tid < 192){
    int d = tid - 64;
    #pragma unroll
    for (int key=0;key<4;key++) vts[d*72 + key] = vdv[(h*4+key)*HDM + d];
  }
  __syncthreads();
  f32x4 s2 = {0.f,0.f,0.f,0.f};
  #pragma unroll
  for (int kc=0;kc<4;kc++){
    s16x8 kf = *(const s16x8*)&kts[c16*136 + (kc*4+g)*8];
    s2 = __builtin_amdgcn_mfma_f32_16x16x32_bf16(qf[kc], kf, s2, 0,0,0);
  }
  bool valid = (c16 < 4);
  float m2[4], l2[4];
  #pragma unroll
  for (int r=0;r<4;r++) m2[r] = valid? s2[r] : -3e38f;
  #pragma unroll
  for (int m=1;m<16;m<<=1)
    #pragma unroll
    for (int r=0;r<4;r++) m2[r] = fmaxf(m2[r], __shfl_xor(m2[r], m));
  #pragma unroll
  for (int r=0;r<4;r++){ float p = valid? __expf(s2[r]-m2[r]) : 0.f; s2[r]=p; l2[r]=p; }
  #pragma unroll
  for (int m=1;m<16;m<<=1)
    #pragma unroll
    for (int r=0;r<4;r++) l2[r] += __shfl_xor(l2[r], m);
  #pragma unroll
  for (int r=0;r<4;r++){
    pwb[(w*16 + g*4 + r)*72 + c16]      = f2b(s2[r]);
    pwb[(w*16 + g*4 + r)*72 + 16 + c16] = (u16)0;
  }
  s16x8 pf2 = *(const s16x8*)&pwb[(w*16 + c16)*72 + g*8];
  f32x4 a2[8];
  #pragma unroll
  for (int dt=0;dt<8;dt++) a2[dt] = f32x4{0.f,0.f,0.f,0.f};
  #pragma unroll
  for (int dt=0;dt<8;dt++){
    s16x8 vf = *(const s16x8*)&vts[(dt*16 + c16)*72 + g*8];
    a2[dt] = __builtin_amdgcn_mfma_f32_16x16x32_bf16(pf2, vf, a2[dt], 0,0,0);
  }
  float sb = bscale[0];
  float rl[4], rl2[4];
  #pragma unroll
  for (int r=0;r<4;r++){ rl[r] = 1.f/l_[r]; rl2[r] = sb/l2[r]; }
  #pragma unroll
  for (int dt=0;dt<8;dt++)
    #pragma unroll
    for (int r=0;r<4;r++){
      int tok = qb + w*16 + g*4 + r;
      int col = h*HDM + dt*16 + c16;
      hs[(size_t)tok*DM + col] = f2b(acc[dt][r]*rl[r] + a2[dt][r]*rl2[r]);
    }
}

extern "C" void kernel_launch(void* const* d_in, const int* in_sizes, int n_in,
                              void* d_out, int out_size, void* d_ws, size_t ws_size,
                              hipStream_t stream){
  static const int expect[28] = {
    6291456, 1572864, 4096, 327680, 327680,
    9437184, 3072, 9437184, 3072, 9437184, 3072, 128, 128,
    9437184, 3072, 9437184, 3072, 9437184, 3072, 128, 128,
    9437184, 3072, 9437184, 3072, 3145728, 3145728, 1 };
  bool ok = (n_in == 28);
  if (ok) for (int i=0;i<28;i++) if (in_sizes[i] != expect[i]) { ok = false; break; }
  if (!ok){ fillv<<<(out_size+255)/256,256,0,stream>>>((float*)d_out, out_size, 7.0f); return; }
  if (ws_size < 119611392ull){ fillv<<<(out_size+255)/256,256,0,stream>>>((float*)d_out, out_size, 9.0f); return; }

  const float* hidden = (const float*)d_in[0];
  const float* enc    = (const float*)d_in[1];
  const float* adapt  = (const float*)d_in[2];
  const float* fcos   = (const float*)d_in[3];
  const float* fsin   = (const float*)d_in[4];
  const float* Wq  = (const float*)d_in[5];  const float* bq  = (const float*)d_in[6];
  const float* Wk  = (const float*)d_in[7];  const float* bk  = (const float*)d_in[8];
  const float* Wv  = (const float*)d_in[9];  const float* bv  = (const float*)d_in[10];
  const float* nqw = (const float*)d_in[11]; const float* nkw = (const float*)d_in[12];
  const float* Wqa = (const float*)d_in[13]; const float* bqa = (const float*)d_in[14];
  const float* Wka = (const float*)d_in[15]; const float* bka = (const float*)d_in[16];
  const float* Wva = (const float*)d_in[17]; const float* bva = (const float*)d_in[18];
  const float* naq = (const float*)d_in[19]; const float* nak = (const float*)d_in[20];
  const float* Wo  = (const float*)d_in[21]; const float* bo  = (const float*)d_in[22];
  const float* Woa = (const float*)d_in[23]; const float* boa = (const float*)d_in[24];
  const float* Wkad = (const float*)d_in[25]; const float* Wvad = (const float*)d_in[26];
  const float* bsc  = (const float*)d_in[27];
  float* out = (float*)d_out;

  // ws layout (bytes), peak ~119.6 MB with lifetime overlap
  char* ws = (char*)d_ws;
  u16* wt3   = (u16*)(ws);                  // [0, 56,623,104): 3 transposed weights
  u16* kh    = (u16*)(ws);                  //   after qkv gemms: kh (15,728,640)
  u16* vth   = (u16*)(ws + 15728640);       //   vth (15,728,640)
  u16* vdk   = (u16*)(ws + 31457280);       //   vdk/vdv (24,576 each)
  u16* vdv   = (u16*)(ws + 31481856);
  u16* woaT  = (u16*)(ws + 33554432);       //   Woa^T (18,874,368)
  u16* hbf   = (u16*)(ws + 56623104);       // hidden bf16 (12,582,912)
  u16* ebf   = (u16*)(ws + 69206016);       // enc bf16 (3,145,728)
  u16* qh    = (u16*)(ws + 56623104);       //   after txt gemm: qh (15,728,640)
  u16* qkvI  = (u16*)(ws + 72351744);       // img QKV [2048][9216]
  u16* hsb   = (u16*)(ws + 72351744);       //   after epi: hsb bf16 [2560][3072]
  u16* woT   = (u16*)(ws + 88080384);       //   Wo^T (18,874,368)
  u16* qkvT  = (u16*)(ws + 110100480);      // txt QKV [512][9216]
  float* biasA = (float*)(ws + 119537664);  // 2x9216 fp32
  float* biasB = (float*)(ws + 119574528);

  cast2<<<3840,256,0,stream>>>(hidden, enc, hbf, 786432, 983040);
  catbias2<<<72,256,0,stream>>>(bq,bk,bv, bqa,bka,bva, biasA);
  ktrans3<<<dim3(48,48,3),256,0,stream>>>(Wq, Wk, Wv, wt3, wt3 + (size_t)DM*DM, wt3 + (size_t)2*DM*DM);
  qkv_gemm<<<dim3(16,72),256,0,stream>>>(hbf, wt3, biasA, qkvI);
  ktrans3<<<dim3(48,48,3),256,0,stream>>>(Wqa, Wka, Wva, wt3, wt3 + (size_t)DM*DM, wt3 + (size_t)2*DM*DM);
  qkv_gemm<<<dim3(4,72),256,0,stream>>>(ebf, wt3, biasB, qkvT);
  epi_fused<<<31680,256,0,stream>>>(qkvI, qkvT, nqw,nkw,naq,nak, fcos,fsin, qh, kh, vth);
  adapterk<<<6144,256,0,stream>>>(adapt, Wkad, Wvad, vdk, vdv);
  attnk<<<dim3(20,24),512,0,stream>>>(qh, kh, vth, vdk, vdv, bsc, hsb);
  ktrans3<<<dim3(48,48,2),256,0,stream>>>(Wo, Woa, Woa, woT, woaT, woaT);
  out_gemm<<<dim3(20,24),256,0,stream>>>(hsb, woT, woaT, bo, boa, out);
}

// Round 11
// 733.813 us; speedup vs baseline: 1.0378x; 1.0378x over previous
//
#include <hip/hip_runtime.h>

typedef unsigned short u16;
typedef short s16x8 __attribute__((ext_vector_type(8)));
typedef float f32x4 __attribute__((ext_vector_type(4)));

#define S_TXTC 512
#define S_TOTC 2560
#define DM 3072
#define NH 24
#define HDM 128

__device__ __forceinline__ float b2f(u16 u){ unsigned int i = ((unsigned int)u)<<16; float f; __builtin_memcpy(&f,&i,4); return f; }
__device__ __forceinline__ u16 f2b(float f){ unsigned int i; __builtin_memcpy(&i,&f,4); unsigned int r = i + 0x7FFFu + ((i>>16)&1u); return (u16)(r>>16); }
__device__ __forceinline__ s16x8 pk8(float4 a, float4 b){
  s16x8 r;
  r[0]=(short)f2b(a.x); r[1]=(short)f2b(a.y); r[2]=(short)f2b(a.z); r[3]=(short)f2b(a.w);
  r[4]=(short)f2b(b.x); r[5]=(short)f2b(b.y); r[6]=(short)f2b(b.z); r[7]=(short)f2b(b.w);
  return r;
}
__device__ __forceinline__ void g2l16(const void* g, void* l){
  __builtin_amdgcn_global_load_lds((const __attribute__((address_space(1))) void*)g,
                                   (__attribute__((address_space(3))) void*)l, 16, 0, 0);
}

__global__ __launch_bounds__(256) void fillv(float* __restrict__ p, int n, float v){
  int i = blockIdx.x*256 + threadIdx.x;
  if (i < n) p[i] = v;
}

// ---------------- cast hidden+enc fp32 -> bf16 (contiguous dest) ----------------
__global__ __launch_bounds__(256) void cast2(const float* __restrict__ a, const float* __restrict__ b,
                                             u16* __restrict__ dst, int na8, int n8){
  int i = blockIdx.x*256 + threadIdx.x;
  if (i >= n8) return;
  const float* src = (i < na8)? a + (size_t)i*8 : b + (size_t)(i-na8)*8;
  float4 f0 = *(const float4*)src;
  float4 f1 = *(const float4*)(src+4);
  *(s16x8*)(dst + (size_t)i*8) = pk8(f0,f1);
}

// ---------------- concat 2x3 biases into 2x9216 fp32 ----------------
__global__ __launch_bounds__(256) void catbias2(const float* __restrict__ b0, const float* __restrict__ b1,
    const float* __restrict__ b2, const float* __restrict__ c0, const float* __restrict__ c1,
    const float* __restrict__ c2, float* __restrict__ dst){
  int i = blockIdx.x*256 + threadIdx.x;
  if (i >= 18432) return;
  int j = (i < 9216)? i : i - 9216;
  const float* s0 = (i<9216)? b0 : c0; const float* s1 = (i<9216)? b1 : c1; const float* s2 = (i<9216)? b2 : c2;
  dst[i] = (j<3072)? s0[j] : (j<6144? s1[j-3072] : s2[j-6144]);
}

// ---------------- transpose+cast up to 3 weights: Wt_bf16[n][k] = W_f32[k][n] ----------------
__global__ __launch_bounds__(256) void ktrans3(const float* __restrict__ W0, const float* __restrict__ W1,
    const float* __restrict__ W2, u16* __restrict__ D0, u16* __restrict__ D1, u16* __restrict__ D2){
  const float* W = (blockIdx.z==0)? W0 : ((blockIdx.z==1)? W1 : W2);
  u16* Wt = (blockIdx.z==0)? D0 : ((blockIdx.z==1)? D1 : D2);
  __shared__ __align__(16) u16 t[64*72];
  int nt = blockIdx.x*64, kt_ = blockIdx.y*64;
  int tid = threadIdx.x;
  #pragma unroll
  for (int i=0;i<2;i++){
    int q = tid + 256*i;
    int r = q>>3, c8 = (q&7)*8;
    float4 f0 = *(const float4*)(W + (size_t)(kt_+r)*DM + nt + c8);
    float4 f1 = *(const float4*)(W + (size_t)(kt_+r)*DM + nt + c8 + 4);
    *(s16x8*)&t[r*72 + c8] = pk8(f0,f1);
  }
  __syncthreads();
  #pragma unroll
  for (int i=0;i<2;i++){
    int q = tid + 256*i;
    int n = q>>3, k8 = (q&7)*8;
    s16x8 v;
    #pragma unroll
    for (int j=0;j<8;j++) v[j] = (short)t[(k8+j)*72 + n];
    *(s16x8*)(Wt + (size_t)(nt+n)*DM + kt_ + k8) = v;
  }
}

// ---------------- m97-style bf16 GEMM core ----------------
template<int OUT32>
__device__ __forceinline__ void gcore(u16* la, u16* lb,
    const u16* __restrict__ A, const u16* __restrict__ Bt,
    const float* __restrict__ bias, void* __restrict__ Cv,
    int ldc, int rb, int crb, int cb){
  const int K = DM;
  int tid = threadIdx.x, w = tid>>6, l = tid&63, g = l>>4, c16 = l&15;
  int wr = (w>>1)*64, wc = (w&1)*64;
  f32x4 acc[4][4] = {};
  const u16* aL = A  + (size_t)(rb + w*32 + (l>>2))*K + (l&3)*8;
  const u16* bL = Bt + (size_t)(cb + w*32 + (l>>2))*K + (l&3)*8;
  u16* laB = la + w*1024;
  u16* lbB = lb + w*1024;
  for (int ks=0; ks<K; ks+=32){
    g2l16(aL + ks,                laB);
    g2l16(aL + 16*(size_t)K + ks, laB + 512);
    g2l16(bL + ks,                lbB);
    g2l16(bL + 16*(size_t)K + ks, lbB + 512);
    __syncthreads();
    s16x8 af[4], bf[4];
    #pragma unroll
    for (int m=0;m<4;m++) af[m] = *(const s16x8*)&la[(wr + m*16 + c16)*32 + g*8];
    #pragma unroll
    for (int n=0;n<4;n++) bf[n] = *(const s16x8*)&lb[(wc + n*16 + c16)*32 + g*8];
    #pragma unroll
    for (int m=0;m<4;m++)
      #pragma unroll
      for (int n=0;n<4;n++)
        acc[m][n] = __builtin_amdgcn_mfma_f32_16x16x32_bf16(af[m], bf[n], acc[m][n], 0,0,0);
    __syncthreads();
  }
  #pragma unroll
  for (int n=0;n<4;n++){
    int col = cb + wc + n*16 + c16;
    float bv = bias[col];
    #pragma unroll
    for (int m=0;m<4;m++){
      int r0 = crb + wr + m*16 + g*4;
      #pragma unroll
      for (int r=0;r<4;r++){
        float oo = acc[m][n][r] + bv;
        if (OUT32) ((float*)Cv)[(size_t)(r0+r)*ldc + col] = oo;
        else       ((u16*)Cv)[(size_t)(r0+r)*ldc + col] = f2b(oo);
      }
    }
  }
}

__global__ __launch_bounds__(256) void qkv_gemm(const u16* __restrict__ A, const u16* __restrict__ Bt,
                                                const float* __restrict__ bias, u16* __restrict__ C){
  __shared__ __align__(16) u16 la[4096];
  __shared__ __align__(16) u16 lb[4096];
  gcore<0>(la, lb, A, Bt, bias, C, 3*DM, blockIdx.x*128, blockIdx.x*128, blockIdx.y*128);
}

__global__ __launch_bounds__(256) void out_gemm(const u16* __restrict__ hsb,
    const u16* __restrict__ woT, const u16* __restrict__ woaT,
    const float* __restrict__ bo, const float* __restrict__ boa, float* __restrict__ out){
  __shared__ __align__(16) u16 la[4096];
  __shared__ __align__(16) u16 lb[4096];
  int bx = blockIdx.x;
  bool txt = (bx < 4);
  int rb = bx*128;
  const u16* Bt = txt? woaT : woT;
  const float* bias = txt? boa : bo;
  float* dst = txt? out + (size_t)2048*DM : out;
  int crb = txt? rb : rb - 512;
  gcore<1>(la, lb, hsb, Bt, bias, dst, DM, rb, crb, blockIdx.y*128);
}

// ---------------- fused epilogues: blocks [0,30720) = qk RMSNorm+RoPE; [30720,31680) = v transpose ----------------
__global__ __launch_bounds__(256) void epi_fused(
    const u16* __restrict__ qkvI, const u16* __restrict__ qkvT,
    const float* __restrict__ nqw, const float* __restrict__ nkw,
    const float* __restrict__ naq, const float* __restrict__ nak,
    const float* __restrict__ fcos, const float* __restrict__ fsin,
    u16* __restrict__ qh, u16* __restrict__ kh, u16* __restrict__ vt){
  __shared__ __align__(16) u16 t[64*136];
  int blk = blockIdx.x;
  if (blk < 30720){
    int wid = blk*4 + (threadIdx.x>>6);
    int lane = threadIdx.x&63;
    int which = wid / (NH*S_TOTC);
    int rem = wid % (NH*S_TOTC);
    int h = rem / S_TOTC, tok = rem % S_TOTC;
    const u16* src = ((tok<S_TXTC)? qkvT + (size_t)tok*(3*DM) : qkvI + (size_t)(tok-S_TXTC)*(3*DM))
                     + which*DM + h*HDM;
    const float* nw = which? ((tok<S_TXTC)? nak : nkw) : ((tok<S_TXTC)? naq : nqw);
    int d = lane*2;
    unsigned int u = *(const unsigned int*)(src + d);
    float x0 = b2f((u16)(u&0xffffu)), x1 = b2f((u16)(u>>16));
    float ss = x0*x0 + x1*x1;
    #pragma unroll
    for (int m=1;m<64;m<<=1) ss += __shfl_xor(ss, m);
    float rr = rsqrtf(ss*(1.f/128.f) + 1e-6f);
    float y0 = x0*rr*nw[d];
    float y1 = x1*rr*nw[d+1];
    float2 cc = *(const float2*)(fcos + (size_t)tok*HDM + d);
    float2 sn = *(const float2*)(fsin + (size_t)tok*HDM + d);
    float sc = which? 1.0f : 0.08838834764831845f;   // fold 1/sqrt(HD) into Q
    float o0 = (y0*cc.x - y1*sn.x)*sc;
    float o1 = (y1*cc.y + y0*sn.y)*sc;
    u16* dst = (which? kh : qh) + ((size_t)h*S_TOTC + tok)*HDM + d;
    *(unsigned int*)dst = (unsigned int)f2b(o0) | ((unsigned int)f2b(o1)<<16);
  } else {
    int bv = blk - 30720;
    int h = bv % NH, tb = bv / NH;
    int tok0 = tb*64, tid = threadIdx.x;
    #pragma unroll
    for (int i=0;i<4;i++){
      int q = tid + 256*i;
      int tr = q>>4, c8 = (q&15)*8;
      int tok = tok0 + tr;
      const u16* src = ((tok<S_TXTC)? qkvT + (size_t)tok*(3*DM) : qkvI + (size_t)(tok-S_TXTC)*(3*DM))
                       + 2*DM + h*HDM;
      *(s16x8*)&t[tr*136 + c8] = *(const s16x8*)(src + c8);
    }
    __syncthreads();
    #pragma unroll
    for (int i=0;i<4;i++){
      int q = tid + 256*i;
      int d = q>>3, j8 = (q&7)*8;
      s16x8 v;
      #pragma unroll
      for (int j=0;j<8;j++) v[j] = (short)t[(j8+j)*136 + d];
      *(s16x8*)(vt + ((size_t)h*HDM + d)*S_TOTC + tok0 + j8) = v;
    }
  }
}

// ---------------- adapter projections: f32 (4x1024)@(1024x3072) -> bf16 [H][4][HD] ----------------
__global__ __launch_bounds__(256) void adapterk(const float* __restrict__ ad, const float* __restrict__ Wk,
        const float* __restrict__ Wv, u16* __restrict__ vdk, u16* __restrict__ vdv){
  int wid = blockIdx.x*4 + (threadIdx.x>>6);
  int lane = threadIdx.x&63;
  int tensor = wid / (4*DM);
  int rem = wid % (4*DM);
  int tok = rem / DM, col = rem % DM;
  const float* Wp = tensor? Wv : Wk;
  float s = 0.f;
  #pragma unroll
  for (int i=0;i<16;i++){
    int k = lane + 64*i;
    s += ad[tok*1024 + k] * Wp[(size_t)k*DM + col];
  }
  #pragma unroll
  for (int m=1;m<64;m<<=1) s += __shfl_xor(s, m);
  if (lane==0){
    int hh = col>>7, d = col&127;
    (tensor? vdv : vdk)[(hh*4+tok)*HDM + d] = f2b(s);
  }
}

// ---------------- fused MFMA flash attention: QBLK=128, 8 waves, KVBLK=64, reg-dbuf, defer-max ----------------
__global__ __launch_bounds__(512,2) void attnk(const u16* __restrict__ qh, const u16* __restrict__ kh,
    const u16* __restrict__ vt, const u16* __restrict__ vdk, const u16* __restrict__ vdv,
    const float* __restrict__ bscale, u16* __restrict__ hs){
  __shared__ __align__(16) u16 kts[64*136];    // [key][d] stride 136
  __shared__ __align__(16) u16 vts[128*72];    // [d][key] stride 72
  __shared__ __align__(16) u16 pwb[128*72];    // [q][key] stride 72
  int h = blockIdx.y, qb = blockIdx.x*128;
  int tid = threadIdx.x, w = tid>>6, l = tid&63, g = l>>4, c16 = l&15;
  int qrow = qb + w*16 + c16;
  s16x8 qf[4];
  #pragma unroll
  for (int kc=0;kc<4;kc++) qf[kc] = *(const s16x8*)(qh + ((size_t)h*S_TOTC + qrow)*HDM + kc*32 + g*8);
  f32x4 acc[8];
  #pragma unroll
  for (int dt=0;dt<8;dt++) acc[dt] = f32x4{0.f,0.f,0.f,0.f};
  float m_[4] = {-3e38f,-3e38f,-3e38f,-3e38f};
  float l_[4] = {0.f,0.f,0.f,0.f};
  const u16* khB = kh + (size_t)h*S_TOTC*HDM;
  const u16* vtB = vt + (size_t)h*HDM*S_TOTC;

  auto LOADT = [&](s16x8* kr, s16x8* vr, int kb){
    #pragma unroll
    for (int i=0;i<2;i++){
      int idx = tid + 512*i;
      kr[i] = *(const s16x8*)(khB + (size_t)(kb + (idx>>4))*HDM + (idx&15)*8);
      vr[i] = *(const s16x8*)(vtB + (size_t)(idx>>3)*S_TOTC + kb + (idx&7)*8);
    }
  };
  auto STORET = [&](s16x8* kr, s16x8* vr){
    #pragma unroll
    for (int i=0;i<2;i++){
      int idx = tid + 512*i;
      *(s16x8*)&kts[(idx>>4)*136 + (idx&15)*8] = kr[i];
      *(s16x8*)&vts[(idx>>3)*72 + (idx&7)*8] = vr[i];
    }
  };
  auto COMPUTE = [&](){
    f32x4 s[4];
    #pragma unroll
    for (int su=0;su<4;su++) s[su] = f32x4{0.f,0.f,0.f,0.f};
    __builtin_amdgcn_s_setprio(1);
    #pragma unroll
    for (int su=0;su<4;su++)
      #pragma unroll
      for (int kc=0;kc<4;kc++){
        s16x8 kf = *(const s16x8*)&kts[(su*16+c16)*136 + (kc*4+g)*8];
        s[su] = __builtin_amdgcn_mfma_f32_16x16x32_bf16(qf[kc], kf, s[su], 0,0,0);
      }
    __builtin_amdgcn_s_setprio(0);
    float tm[4];
    #pragma unroll
    for (int r=0;r<4;r++)
      tm[r] = fmaxf(fmaxf(s[0][r],s[1][r]), fmaxf(s[2][r],s[3][r]));
    #pragma unroll
    for (int m=1;m<16;m<<=1)
      #pragma unroll
      for (int r=0;r<4;r++) tm[r] = fmaxf(tm[r], __shfl_xor(tm[r], m));
    bool need = !__all(tm[0]<=m_[0]+8.f && tm[1]<=m_[1]+8.f && tm[2]<=m_[2]+8.f && tm[3]<=m_[3]+8.f);
    if (need){
      float corr[4];
      #pragma unroll
      for (int r=0;r<4;r++){
        float mn = fmaxf(m_[r], tm[r]);
        corr[r] = __expf(m_[r]-mn);
        m_[r] = mn;
        l_[r] *= corr[r];
      }
      #pragma unroll
      for (int dt=0;dt<8;dt++)
        #pragma unroll
        for (int r=0;r<4;r++) acc[dt][r] *= corr[r];
    }
    float rs[4];
    #pragma unroll
    for (int r=0;r<4;r++){
      rs[r] = 0.f;
      #pragma unroll
      for (int su=0;su<4;su++){ s[su][r] = __expf(s[su][r]-m_[r]); rs[r] += s[su][r]; }
    }
    #pragma unroll
    for (int m=1;m<16;m<<=1)
      #pragma unroll
      for (int r=0;r<4;r++) rs[r] += __shfl_xor(rs[r], m);
    #pragma unroll
    for (int r=0;r<4;r++) l_[r] += rs[r];
    #pragma unroll
    for (int su=0;su<4;su++)
      #pragma unroll
      for (int r=0;r<4;r++)
        pwb[(w*16 + g*4 + r)*72 + su*16 + c16] = f2b(s[su][r]);
    s16x8 pf0 = *(const s16x8*)&pwb[(w*16 + c16)*72 + g*8];
    s16x8 pf1 = *(const s16x8*)&pwb[(w*16 + c16)*72 + 32 + g*8];
    __builtin_amdgcn_s_setprio(1);
    #pragma unroll
    for (int dt=0;dt<8;dt++){
      s16x8 vf0 = *(const s16x8*)&vts[(dt*16 + c16)*72 + g*8];
      acc[dt] = __builtin_amdgcn_mfma_f32_16x16x32_bf16(pf0, vf0, acc[dt], 0,0,0);
      s16x8 vf1 = *(const s16x8*)&vts[(dt*16 + c16)*72 + 32 + g*8];
      acc[dt] = __builtin_amdgcn_mfma_f32_16x16x32_bf16(pf1, vf1, acc[dt], 0,0,0);
    }
    __builtin_amdgcn_s_setprio(0);
  };

  s16x8 ka[2], va[2], kb2[2], vb2[2];
  LOADT(ka, va, 0);
  for (int kb=0; kb<S_TOTC; kb+=128){
    STORET(ka, va);
    __syncthreads();
    LOADT(kb2, vb2, kb+64);
    COMPUTE();
    __syncthreads();
    STORET(kb2, vb2);
    __syncthreads();
    if (kb+128 < S_TOTC) LOADT(ka, va, kb+128);
    COMPUTE();
    __syncthreads();
  }

  // adapter cross-attention: stage 4 K rows / 4 V keys into kts/vts (stale rest is masked)
  if (tid < 64){
    int key = tid>>4, c8 = (tid&15)*8;
    *(s16x8*)&kts[key*136 + c8] = *(const s16x8*)(vdk + (h*4+key)*HDM + c8);
  } else if (tid < 192){
    int d = tid - 64;
    #pragma unroll
    for (int key=0;key<4;key++) vts[d*72 + key] = vdv[(h*4+key)*HDM + d];
  }
  __syncthreads();
  f32x4 s2 = {0.f,0.f,0.f,0.f};
  #pragma unroll
  for (int kc=0;kc<4;kc++){
    s16x8 kf = *(const s16x8*)&kts[c16*136 + (kc*4+g)*8];
    s2 = __builtin_amdgcn_mfma_f32_16x16x32_bf16(qf[kc], kf, s2, 0,0,0);
  }
  bool valid = (c16 < 4);
  float m2[4], l2[4];
  #pragma unroll
  for (int r=0;r<4;r++) m2[r] = valid? s2[r] : -3e38f;
  #pragma unroll
  for (int m=1;m<16;m<<=1)
    #pragma unroll
    for (int r=0;r<4;r++) m2[r] = fmaxf(m2[r], __shfl_xor(m2[r], m));
  #pragma unroll
  for (int r=0;r<4;r++){ float p = valid? __expf(s2[r]-m2[r]) : 0.f; s2[r]=p; l2[r]=p; }
  #pragma unroll
  for (int m=1;m<16;m<<=1)
    #pragma unroll
    for (int r=0;r<4;r++) l2[r] += __shfl_xor(l2[r], m);
  #pragma unroll
  for (int r=0;r<4;r++){
    pwb[(w*16 + g*4 + r)*72 + c16]      = f2b(s2[r]);
    pwb[(w*16 + g*4 + r)*72 + 16 + c16] = (u16)0;
  }
  s16x8 pf2 = *(const s16x8*)&pwb[(w*16 + c16)*72 + g*8];
  f32x4 a2[8];
  #pragma unroll
  for (int dt=0;dt<8;dt++) a2[dt] = f32x4{0.f,0.f,0.f,0.f};
  #pragma unroll
  for (int dt=0;dt<8;dt++){
    s16x8 vf = *(const s16x8*)&vts[(dt*16 + c16)*72 + g*8];
    a2[dt] = __builtin_amdgcn_mfma_f32_16x16x32_bf16(pf2, vf, a2[dt], 0,0,0);
  }
  float sb = bscale[0];
  float rl[4], rl2[4];
  #pragma unroll
  for (int r=0;r<4;r++){ rl[r] = 1.f/l_[r]; rl2[r] = sb/l2[r]; }
  #pragma unroll
  for (int dt=0;dt<8;dt++)
    #pragma unroll
    for (int r=0;r<4;r++){
      int tok = qb + w*16 + g*4 + r;
      int col = h*HDM + dt*16 + c16;
      hs[(size_t)tok*DM + col] = f2b(acc[dt][r]*rl[r] + a2[dt][r]*rl2[r]);
    }
}

extern "C" void kernel_launch(void* const* d_in, const int* in_sizes, int n_in,
                              void* d_out, int out_size, void* d_ws, size_t ws_size,
                              hipStream_t stream){
  static const int expect[28] = {
    6291456, 1572864, 4096, 327680, 327680,
    9437184, 3072, 9437184, 3072, 9437184, 3072, 128, 128,
    9437184, 3072, 9437184, 3072, 9437184, 3072, 128, 128,
    9437184, 3072, 9437184, 3072, 3145728, 3145728, 1 };
  bool ok = (n_in == 28);
  if (ok) for (int i=0;i<28;i++) if (in_sizes[i] != expect[i]) { ok = false; break; }
  if (!ok){ fillv<<<(out_size+255)/256,256,0,stream>>>((float*)d_out, out_size, 7.0f); return; }
  if (ws_size < 119611392ull){ fillv<<<(out_size+255)/256,256,0,stream>>>((float*)d_out, out_size, 9.0f); return; }

  const float* hidden = (const float*)d_in[0];
  const float* enc    = (const float*)d_in[1];
  const float* adapt  = (const float*)d_in[2];
  const float* fcos   = (const float*)d_in[3];
  const float* fsin   = (const float*)d_in[4];
  const float* Wq  = (const float*)d_in[5];  const float* bq  = (const float*)d_in[6];
  const float* Wk  = (const float*)d_in[7];  const float* bk  = (const float*)d_in[8];
  const float* Wv  = (const float*)d_in[9];  const float* bv  = (const float*)d_in[10];
  const float* nqw = (const float*)d_in[11]; const float* nkw = (const float*)d_in[12];
  const float* Wqa = (const float*)d_in[13]; const float* bqa = (const float*)d_in[14];
  const float* Wka = (const float*)d_in[15]; const float* bka = (const float*)d_in[16];
  const float* Wva = (const float*)d_in[17]; const float* bva = (const float*)d_in[18];
  const float* naq = (const float*)d_in[19]; const float* nak = (const float*)d_in[20];
  const float* Wo  = (const float*)d_in[21]; const float* bo  = (const float*)d_in[22];
  const float* Woa = (const float*)d_in[23]; const float* boa = (const float*)d_in[24];
  const float* Wkad = (const float*)d_in[25]; const float* Wvad = (const float*)d_in[26];
  const float* bsc  = (const float*)d_in[27];
  float* out = (float*)d_out;

  // ws layout (bytes), peak ~119.6 MB with lifetime overlap
  char* ws = (char*)d_ws;
  u16* wt3   = (u16*)(ws);                  // [0, 56,623,104): 3 transposed weights
  u16* kh    = (u16*)(ws);                  //   after qkv gemms: kh (15,728,640)
  u16* vth   = (u16*)(ws + 15728640);       //   vth (15,728,640)
  u16* vdk   = (u16*)(ws + 31457280);       //   vdk/vdv (24,576 each)
  u16* vdv   = (u16*)(ws + 31481856);
  u16* woaT  = (u16*)(ws + 33554432);       //   Woa^T (18,874,368)
  u16* hbf   = (u16*)(ws + 56623104);       // hidden bf16 (12,582,912)
  u16* ebf   = (u16*)(ws + 69206016);       // enc bf16 (3,145,728)
  u16* qh    = (u16*)(ws + 56623104);       //   after txt gemm: qh (15,728,640)
  u16* qkvI  = (u16*)(ws + 72351744);       // img QKV [2048][9216]
  u16* hsb   = (u16*)(ws + 72351744);       //   after epi: hsb bf16 [2560][3072]
  u16* woT   = (u16*)(ws + 88080384);       //   Wo^T (18,874,368)
  u16* qkvT  = (u16*)(ws + 110100480);      // txt QKV [512][9216]
  float* biasA = (float*)(ws + 119537664);  // 2x9216 fp32
  float* biasB = (float*)(ws + 119574528);

  cast2<<<3840,256,0,stream>>>(hidden, enc, hbf, 786432, 983040);
  catbias2<<<72,256,0,stream>>>(bq,bk,bv, bqa,bka,bva, biasA);
  ktrans3<<<dim3(48,48,3),256,0,stream>>>(Wq, Wk, Wv, wt3, wt3 + (size_t)DM*DM, wt3 + (size_t)2*DM*DM);
  qkv_gemm<<<dim3(16,72),256,0,stream>>>(hbf, wt3, biasA, qkvI);
  ktrans3<<<dim3(48,48,3),256,0,stream>>>(Wqa, Wka, Wva, wt3, wt3 + (size_t)DM*DM, wt3 + (size_t)2*DM*DM);
  qkv_gemm<<<dim3(4,72),256,0,stream>>>(ebf, wt3, biasB, qkvT);
  epi_fused<<<31680,256,0,stream>>>(qkvI, qkvT, nqw,nkw,naq,nak, fcos,fsin, qh, kh, vth);
  adapterk<<<6144,256,0,stream>>>(adapt, Wkad, Wvad, vdk, vdv);
  attnk<<<dim3(20,24),512,0,stream>>>(qh, kh, vth, vdk, vdv, bsc, hsb);
  ktrans3<<<dim3(48,48,2),256,0,stream>>>(Wo, Woa, Woa, woT, woaT, woaT);
  out_gemm<<<dim3(20,24),256,0,stream>>>(hsb, woT, woaT, bo, boa, out);
}

// Round 12
// 713.247 us; speedup vs baseline: 1.0677x; 1.0288x over previous
//
#include <hip/hip_runtime.h>

typedef unsigned short u16;
typedef short s16x8 __attribute__((ext_vector_type(8)));
typedef float f32x4 __attribute__((ext_vector_type(4)));

#define S_TXTC 512
#define S_TOTC 2560
#define DM 3072
#define NH 24
#define HDM 128

__device__ __forceinline__ float b2f(u16 u){ unsigned int i = ((unsigned int)u)<<16; float f; __builtin_memcpy(&f,&i,4); return f; }
__device__ __forceinline__ u16 f2b(float f){ unsigned int i; __builtin_memcpy(&i,&f,4); unsigned int r = i + 0x7FFFu + ((i>>16)&1u); return (u16)(r>>16); }
__device__ __forceinline__ s16x8 pk8(float4 a, float4 b){
  s16x8 r;
  r[0]=(short)f2b(a.x); r[1]=(short)f2b(a.y); r[2]=(short)f2b(a.z); r[3]=(short)f2b(a.w);
  r[4]=(short)f2b(b.x); r[5]=(short)f2b(b.y); r[6]=(short)f2b(b.z); r[7]=(short)f2b(b.w);
  return r;
}
__device__ __forceinline__ void g2l16(const void* g, void* l){
  __builtin_amdgcn_global_load_lds((const __attribute__((address_space(1))) void*)g,
                                   (__attribute__((address_space(3))) void*)l, 16, 0, 0);
}

__global__ __launch_bounds__(256) void fillv(float* __restrict__ p, int n, float v){
  int i = blockIdx.x*256 + threadIdx.x;
  if (i < n) p[i] = v;
}

__global__ __launch_bounds__(256) void cast2(const float* __restrict__ a, const float* __restrict__ b,
                                             u16* __restrict__ dst, int na8, int n8){
  int i = blockIdx.x*256 + threadIdx.x;
  if (i >= n8) return;
  const float* src = (i < na8)? a + (size_t)i*8 : b + (size_t)(i-na8)*8;
  float4 f0 = *(const float4*)src;
  float4 f1 = *(const float4*)(src+4);
  *(s16x8*)(dst + (size_t)i*8) = pk8(f0,f1);
}

__global__ __launch_bounds__(256) void catbias2(const float* __restrict__ b0, const float* __restrict__ b1,
    const float* __restrict__ b2, const float* __restrict__ c0, const float* __restrict__ c1,
    const float* __restrict__ c2, float* __restrict__ dst){
  int i = blockIdx.x*256 + threadIdx.x;
  if (i >= 18432) return;
  int j = (i < 9216)? i : i - 9216;
  const float* s0 = (i<9216)? b0 : c0; const float* s1 = (i<9216)? b1 : c1; const float* s2 = (i<9216)? b2 : c2;
  dst[i] = (j<3072)? s0[j] : (j<6144? s1[j-3072] : s2[j-6144]);
}

__global__ __launch_bounds__(256) void ktrans3(const float* __restrict__ W0, const float* __restrict__ W1,
    const float* __restrict__ W2, u16* __restrict__ D0, u16* __restrict__ D1, u16* __restrict__ D2){
  const float* W = (blockIdx.z==0)? W0 : ((blockIdx.z==1)? W1 : W2);
  u16* Wt = (blockIdx.z==0)? D0 : ((blockIdx.z==1)? D1 : D2);
  __shared__ __align__(16) u16 t[64*72];
  int nt = blockIdx.x*64, kt_ = blockIdx.y*64;
  int tid = threadIdx.x;
  #pragma unroll
  for (int i=0;i<2;i++){
    int q = tid + 256*i;
    int r = q>>3, c8 = (q&7)*8;
    float4 f0 = *(const float4*)(W + (size_t)(kt_+r)*DM + nt + c8);
    float4 f1 = *(const float4*)(W + (size_t)(kt_+r)*DM + nt + c8 + 4);
    *(s16x8*)&t[r*72 + c8] = pk8(f0,f1);
  }
  __syncthreads();
  #pragma unroll
  for (int i=0;i<2;i++){
    int q = tid + 256*i;
    int n = q>>3, k8 = (q&7)*8;
    s16x8 v;
    #pragma unroll
    for (int j=0;j<8;j++) v[j] = (short)t[(k8+j)*72 + n];
    *(s16x8*)(Wt + (size_t)(nt+n)*DM + kt_ + k8) = v;
  }
}

// ---------------- m97-style bf16 GEMM core ----------------
template<int OUT32>
__device__ __forceinline__ void gcore(u16* la, u16* lb,
    const u16* __restrict__ A, const u16* __restrict__ Bt,
    const float* __restrict__ bias, void* __restrict__ Cv,
    int ldc, int rb, int crb, int cb){
  const int K = DM;
  int tid = threadIdx.x, w = tid>>6, l = tid&63, g = l>>4, c16 = l&15;
  int wr = (w>>1)*64, wc = (w&1)*64;
  f32x4 acc[4][4] = {};
  const u16* aL = A  + (size_t)(rb + w*32 + (l>>2))*K + (l&3)*8;
  const u16* bL = Bt + (size_t)(cb + w*32 + (l>>2))*K + (l&3)*8;
  u16* laB = la + w*1024;
  u16* lbB = lb + w*1024;
  for (int ks=0; ks<K; ks+=32){
    g2l16(aL + ks,                laB);
    g2l16(aL + 16*(size_t)K + ks, laB + 512);
    g2l16(bL + ks,                lbB);
    g2l16(bL + 16*(size_t)K + ks, lbB + 512);
    __syncthreads();
    s16x8 af[4], bf[4];
    #pragma unroll
    for (int m=0;m<4;m++) af[m] = *(const s16x8*)&la[(wr + m*16 + c16)*32 + g*8];
    #pragma unroll
    for (int n=0;n<4;n++) bf[n] = *(const s16x8*)&lb[(wc + n*16 + c16)*32 + g*8];
    #pragma unroll
    for (int m=0;m<4;m++)
      #pragma unroll
      for (int n=0;n<4;n++)
        acc[m][n] = __builtin_amdgcn_mfma_f32_16x16x32_bf16(af[m], bf[n], acc[m][n], 0,0,0);
    __syncthreads();
  }
  #pragma unroll
  for (int n=0;n<4;n++){
    int col = cb + wc + n*16 + c16;
    float bv = bias[col];
    #pragma unroll
    for (int m=0;m<4;m++){
      int r0 = crb + wr + m*16 + g*4;
      #pragma unroll
      for (int r=0;r<4;r++){
        float oo = acc[m][n][r] + bv;
        if (OUT32) ((float*)Cv)[(size_t)(r0+r)*ldc + col] = oo;
        else       ((u16*)Cv)[(size_t)(r0+r)*ldc + col] = f2b(oo);
      }
    }
  }
}

// XCD-chunked bijective block swizzle (requires nwg % 8 == 0)
__device__ __forceinline__ void xcd_swz(int& bx, int& by){
  int gx = gridDim.x, nwg = gx*gridDim.y;
  int id = blockIdx.y*gx + blockIdx.x;
  int q = nwg>>3;
  int nid = (id&7)*q + (id>>3);
  bx = nid % gx; by = nid / gx;
}

__global__ __launch_bounds__(256) void qkv_gemm(const u16* __restrict__ A, const u16* __restrict__ Bt,
                                                const float* __restrict__ bias, u16* __restrict__ C){
  __shared__ __align__(16) u16 la[4096];
  __shared__ __align__(16) u16 lb[4096];
  int bx, by; xcd_swz(bx, by);
  gcore<0>(la, lb, A, Bt, bias, C, 3*DM, bx*128, bx*128, by*128);
}

__global__ __launch_bounds__(256) void out_gemm(const u16* __restrict__ hsb,
    const u16* __restrict__ woT, const u16* __restrict__ woaT,
    const float* __restrict__ bo, const float* __restrict__ boa, float* __restrict__ out){
  __shared__ __align__(16) u16 la[4096];
  __shared__ __align__(16) u16 lb[4096];
  int bx, by; xcd_swz(bx, by);
  bool txt = (bx < 4);
  int rb = bx*128;
  const u16* Bt = txt? woaT : woT;
  const float* bias = txt? boa : bo;
  float* dst = txt? out + (size_t)2048*DM : out;
  int crb = txt? rb : rb - 512;
  gcore<1>(la, lb, hsb, Bt, bias, dst, DM, rb, crb, by*128);
}

// ---------------- fused epilogues ----------------
__global__ __launch_bounds__(256) void epi_fused(
    const u16* __restrict__ qkvI, const u16* __restrict__ qkvT,
    const float* __restrict__ nqw, const float* __restrict__ nkw,
    const float* __restrict__ naq, const float* __restrict__ nak,
    const float* __restrict__ fcos, const float* __restrict__ fsin,
    u16* __restrict__ qh, u16* __restrict__ kh, u16* __restrict__ vt){
  __shared__ __align__(16) u16 t[64*136];
  int blk = blockIdx.x;
  if (blk < 30720){
    int wid = blk*4 + (threadIdx.x>>6);
    int lane = threadIdx.x&63;
    int which = wid / (NH*S_TOTC);
    int rem = wid % (NH*S_TOTC);
    int h = rem / S_TOTC, tok = rem % S_TOTC;
    const u16* src = ((tok<S_TXTC)? qkvT + (size_t)tok*(3*DM) : qkvI + (size_t)(tok-S_TXTC)*(3*DM))
                     + which*DM + h*HDM;
    const float* nw = which? ((tok<S_TXTC)? nak : nkw) : ((tok<S_TXTC)? naq : nqw);
    int d = lane*2;
    unsigned int u = *(const unsigned int*)(src + d);
    float x0 = b2f((u16)(u&0xffffu)), x1 = b2f((u16)(u>>16));
    float ss = x0*x0 + x1*x1;
    #pragma unroll
    for (int m=1;m<64;m<<=1) ss += __shfl_xor(ss, m);
    float rr = rsqrtf(ss*(1.f/128.f) + 1e-6f);
    float y0 = x0*rr*nw[d];
    float y1 = x1*rr*nw[d+1];
    float2 cc = *(const float2*)(fcos + (size_t)tok*HDM + d);
    float2 sn = *(const float2*)(fsin + (size_t)tok*HDM + d);
    float sc = which? 1.0f : 0.08838834764831845f;
    float o0 = (y0*cc.x - y1*sn.x)*sc;
    float o1 = (y1*cc.y + y0*sn.y)*sc;
    u16* dst = (which? kh : qh) + ((size_t)h*S_TOTC + tok)*HDM + d;
    *(unsigned int*)dst = (unsigned int)f2b(o0) | ((unsigned int)f2b(o1)<<16);
  } else {
    int bv = blk - 30720;
    int h = bv % NH, tb = bv / NH;
    int tok0 = tb*64, tid = threadIdx.x;
    #pragma unroll
    for (int i=0;i<4;i++){
      int q = tid + 256*i;
      int tr = q>>4, c8 = (q&15)*8;
      int tok = tok0 + tr;
      const u16* src = ((tok<S_TXTC)? qkvT + (size_t)tok*(3*DM) : qkvI + (size_t)(tok-S_TXTC)*(3*DM))
                       + 2*DM + h*HDM;
      *(s16x8*)&t[tr*136 + c8] = *(const s16x8*)(src + c8);
    }
    __syncthreads();
    #pragma unroll
    for (int i=0;i<4;i++){
      int q = tid + 256*i;
      int d = q>>3, j8 = (q&7)*8;
      s16x8 v;
      #pragma unroll
      for (int j=0;j<8;j++) v[j] = (short)t[(j8+j)*136 + d];
      *(s16x8*)(vt + ((size_t)h*HDM + d)*S_TOTC + tok0 + j8) = v;
    }
  }
}

__global__ __launch_bounds__(256) void adapterk(const float* __restrict__ ad, const float* __restrict__ Wk,
        const float* __restrict__ Wv, u16* __restrict__ vdk, u16* __restrict__ vdv){
  int wid = blockIdx.x*4 + (threadIdx.x>>6);
  int lane = threadIdx.x&63;
  int tensor = wid / (4*DM);
  int rem = wid % (4*DM);
  int tok = rem / DM, col = rem % DM;
  const float* Wp = tensor? Wv : Wk;
  float s = 0.f;
  #pragma unroll
  for (int i=0;i<16;i++){
    int k = lane + 64*i;
    s += ad[tok*1024 + k] * Wp[(size_t)k*DM + col];
  }
  #pragma unroll
  for (int m=1;m<64;m<<=1) s += __shfl_xor(s, m);
  if (lane==0){
    int hh = col>>7, d = col&127;
    (tensor? vdv : vdk)[(hh*4+tok)*HDM + d] = f2b(s);
  }
}

// ---------------- attn: QBLK=128, 8 waves, KVBLK=64, linear 16KB tiles + XOR swizzle, 48KB LDS ----------------
__global__ __launch_bounds__(512,2) void attnk(const u16* __restrict__ qh, const u16* __restrict__ kh,
    const u16* __restrict__ vt, const u16* __restrict__ vdk, const u16* __restrict__ vdv,
    const float* __restrict__ bscale, u16* __restrict__ hs){
  __shared__ __align__(16) u16 kts[64*128];    // [key][d], 16 slots/row, slot ^= row&7
  __shared__ __align__(16) u16 vts[128*64];    // [d][key], 8 slots/row, slot ^= row&7
  __shared__ __align__(16) u16 pwb[128*64];    // [q][key], 8 slots/row, slot ^= row&7
  int h = blockIdx.y, qb = blockIdx.x*128;
  int tid = threadIdx.x, w = tid>>6, l = tid&63, g = l>>4, c16 = l&15;
  int qrow = qb + w*16 + c16;
  int c7 = c16&7;
  s16x8 qf[4];
  #pragma unroll
  for (int kc=0;kc<4;kc++) qf[kc] = *(const s16x8*)(qh + ((size_t)h*S_TOTC + qrow)*HDM + kc*32 + g*8);
  f32x4 acc[8];
  #pragma unroll
  for (int dt=0;dt<8;dt++) acc[dt] = f32x4{0.f,0.f,0.f,0.f};
  float m_[4] = {-3e38f,-3e38f,-3e38f,-3e38f};
  float l_[4] = {0.f,0.f,0.f,0.f};
  const u16* khB = kh + (size_t)h*S_TOTC*HDM;
  const u16* vtB = vt + (size_t)h*HDM*S_TOTC;

  auto LOADT = [&](s16x8* kr, s16x8* vr, int kb){
    #pragma unroll
    for (int i=0;i<2;i++){
      int idx = tid + 512*i;
      kr[i] = *(const s16x8*)(khB + (size_t)(kb + (idx>>4))*HDM + (idx&15)*8);
      vr[i] = *(const s16x8*)(vtB + (size_t)(idx>>3)*S_TOTC + kb + (idx&7)*8);
    }
  };
  auto STORET = [&](s16x8* kr, s16x8* vr){
    #pragma unroll
    for (int i=0;i<2;i++){
      int idx = tid + 512*i;
      int krow = idx>>4, kslot = (idx&15) ^ (krow&7);
      *(s16x8*)&kts[krow*128 + kslot*8] = kr[i];
      int vrow = idx>>3, vslot = (idx&7) ^ (vrow&7);
      *(s16x8*)&vts[vrow*64 + vslot*8] = vr[i];
    }
  };
  auto COMPUTE = [&](){
    f32x4 s[4];
    #pragma unroll
    for (int su=0;su<4;su++) s[su] = f32x4{0.f,0.f,0.f,0.f};
    __builtin_amdgcn_s_setprio(1);
    #pragma unroll
    for (int su=0;su<4;su++)
      #pragma unroll
      for (int kc=0;kc<4;kc++){
        s16x8 kf = *(const s16x8*)&kts[(su*16+c16)*128 + ((kc*4+g) ^ c7)*8];
        s[su] = __builtin_amdgcn_mfma_f32_16x16x32_bf16(qf[kc], kf, s[su], 0,0,0);
      }
    __builtin_amdgcn_s_setprio(0);
    float tm[4];
    #pragma unroll
    for (int r=0;r<4;r++)
      tm[r] = fmaxf(fmaxf(s[0][r],s[1][r]), fmaxf(s[2][r],s[3][r]));
    #pragma unroll
    for (int m=1;m<16;m<<=1)
      #pragma unroll
      for (int r=0;r<4;r++) tm[r] = fmaxf(tm[r], __shfl_xor(tm[r], m));
    bool need = !__all(tm[0]<=m_[0]+8.f && tm[1]<=m_[1]+8.f && tm[2]<=m_[2]+8.f && tm[3]<=m_[3]+8.f);
    if (need){
      float corr[4];
      #pragma unroll
      for (int r=0;r<4;r++){
        float mn = fmaxf(m_[r], tm[r]);
        corr[r] = __expf(m_[r]-mn);
        m_[r] = mn;
        l_[r] *= corr[r];
      }
      #pragma unroll
      for (int dt=0;dt<8;dt++)
        #pragma unroll
        for (int r=0;r<4;r++) acc[dt][r] *= corr[r];
    }
    float rs[4];
    #pragma unroll
    for (int r=0;r<4;r++){
      rs[r] = 0.f;
      #pragma unroll
      for (int su=0;su<4;su++){ s[su][r] = __expf(s[su][r]-m_[r]); rs[r] += s[su][r]; }
    }
    #pragma unroll
    for (int m=1;m<16;m<<=1)
      #pragma unroll
      for (int r=0;r<4;r++) rs[r] += __shfl_xor(rs[r], m);
    #pragma unroll
    for (int r=0;r<4;r++) l_[r] += rs[r];
    // P store: row = w*16+g*4+r, key = su*16+c16 -> slot (key>>3) ^ (row&7), elem key&7
    #pragma unroll
    for (int su=0;su<4;su++){
      int kslot = su*2 + (c16>>3);
      #pragma unroll
      for (int r=0;r<4;r++){
        int prow = w*16 + g*4 + r;
        pwb[prow*64 + (kslot ^ (prow&7))*8 + c7] = f2b(s[su][r]);
      }
    }
    int prow = w*16 + c16;
    s16x8 pf0 = *(const s16x8*)&pwb[prow*64 + ((0+g) ^ c7)*8];
    s16x8 pf1 = *(const s16x8*)&pwb[prow*64 + ((4+g) ^ c7)*8];
    __builtin_amdgcn_s_setprio(1);
    #pragma unroll
    for (int dt=0;dt<8;dt++){
      int vrow = dt*16 + c16;
      s16x8 vf0 = *(const s16x8*)&vts[vrow*64 + ((0+g) ^ c7)*8];
      acc[dt] = __builtin_amdgcn_mfma_f32_16x16x32_bf16(pf0, vf0, acc[dt], 0,0,0);
      s16x8 vf1 = *(const s16x8*)&vts[vrow*64 + ((4+g) ^ c7)*8];
      acc[dt] = __builtin_amdgcn_mfma_f32_16x16x32_bf16(pf1, vf1, acc[dt], 0,0,0);
    }
    __builtin_amdgcn_s_setprio(0);
  };

  s16x8 ka[2], va[2], kb2[2], vb2[2];
  LOADT(ka, va, 0);
  for (int kb=0; kb<S_TOTC; kb+=128){
    STORET(ka, va);
    __syncthreads();
    LOADT(kb2, vb2, kb+64);
    COMPUTE();
    __syncthreads();
    STORET(kb2, vb2);
    __syncthreads();
    if (kb+128 < S_TOTC) LOADT(ka, va, kb+128);
    COMPUTE();
    __syncthreads();
  }

  // adapter cross-attention: stage 4 K rows / 4 V keys (swizzled), stale rest masked by P=0
  if (tid < 64){
    int row = tid>>4, slot = (tid&15) ^ (row&7);
    *(s16x8*)&kts[row*128 + slot*8] = *(const s16x8*)(vdk + (h*4+(tid>>4))*HDM + (tid&15)*8);
  } else if (tid < 192){
    int d = tid - 64;
    int sl0 = (0 ^ (d&7))*8;
    #pragma unroll
    for (int key=0;key<4;key++) vts[d*64 + sl0 + key] = vdv[(h*4+key)*HDM + d];
  }
  __syncthreads();
  f32x4 s2 = {0.f,0.f,0.f,0.f};
  #pragma unroll
  for (int kc=0;kc<4;kc++){
    s16x8 kf = *(const s16x8*)&kts[c16*128 + ((kc*4+g) ^ c7)*8];
    s2 = __builtin_amdgcn_mfma_f32_16x16x32_bf16(qf[kc], kf, s2, 0,0,0);
  }
  bool valid = (c16 < 4);
  float m2[4], l2[4];
  #pragma unroll
  for (int r=0;r<4;r++) m2[r] = valid? s2[r] : -3e38f;
  #pragma unroll
  for (int m=1;m<16;m<<=1)
    #pragma unroll
    for (int r=0;r<4;r++) m2[r] = fmaxf(m2[r], __shfl_xor(m2[r], m));
  #pragma unroll
  for (int r=0;r<4;r++){ float p = valid? __expf(s2[r]-m2[r]) : 0.f; s2[r]=p; l2[r]=p; }
  #pragma unroll
  for (int m=1;m<16;m<<=1)
    #pragma unroll
    for (int r=0;r<4;r++) l2[r] += __shfl_xor(l2[r], m);
  #pragma unroll
  for (int r=0;r<4;r++){
    int prow = w*16 + g*4 + r;
    int s0 = (c16>>3) ^ (prow&7);
    int s1 = (2 + (c16>>3)) ^ (prow&7);
    pwb[prow*64 + s0*8 + c7] = f2b(s2[r]);
    pwb[prow*64 + s1*8 + c7] = (u16)0;
  }
  int prow2 = w*16 + c16;
  s16x8 pf2 = *(const s16x8*)&pwb[prow2*64 + (g ^ c7)*8];
  f32x4 a2[8];
  #pragma unroll
  for (int dt=0;dt<8;dt++) a2[dt] = f32x4{0.f,0.f,0.f,0.f};
  #pragma unroll
  for (int dt=0;dt<8;dt++){
    int vrow = dt*16 + c16;
    s16x8 vf = *(const s16x8*)&vts[vrow*64 + (g ^ c7)*8];
    a2[dt] = __builtin_amdgcn_mfma_f32_16x16x32_bf16(pf2, vf, a2[dt], 0,0,0);
  }
  float sb = bscale[0];
  float rl[4], rl2[4];
  #pragma unroll
  for (int r=0;r<4;r++){ rl[r] = 1.f/l_[r]; rl2[r] = sb/l2[r]; }
  #pragma unroll
  for (int dt=0;dt<8;dt++)
    #pragma unroll
    for (int r=0;r<4;r++){
      int tok = qb + w*16 + g*4 + r;
      int col = h*HDM + dt*16 + c16;
      hs[(size_t)tok*DM + col] = f2b(acc[dt][r]*rl[r] + a2[dt][r]*rl2[r]);
    }
}

extern "C" void kernel_launch(void* const* d_in, const int* in_sizes, int n_in,
                              void* d_out, int out_size, void* d_ws, size_t ws_size,
                              hipStream_t stream){
  static const int expect[28] = {
    6291456, 1572864, 4096, 327680, 327680,
    9437184, 3072, 9437184, 3072, 9437184, 3072, 128, 128,
    9437184, 3072, 9437184, 3072, 9437184, 3072, 128, 128,
    9437184, 3072, 9437184, 3072, 3145728, 3145728, 1 };
  bool ok = (n_in == 28);
  if (ok) for (int i=0;i<28;i++) if (in_sizes[i] != expect[i]) { ok = false; break; }
  if (!ok){ fillv<<<(out_size+255)/256,256,0,stream>>>((float*)d_out, out_size, 7.0f); return; }
  if (ws_size < 119611392ull){ fillv<<<(out_size+255)/256,256,0,stream>>>((float*)d_out, out_size, 9.0f); return; }

  const float* hidden = (const float*)d_in[0];
  const float* enc    = (const float*)d_in[1];
  const float* adapt  = (const float*)d_in[2];
  const float* fcos   = (const float*)d_in[3];
  const float* fsin   = (const float*)d_in[4];
  const float* Wq  = (const float*)d_in[5];  const float* bq  = (const float*)d_in[6];
  const float* Wk  = (const float*)d_in[7];  const float* bk  = (const float*)d_in[8];
  const float* Wv  = (const float*)d_in[9];  const float* bv  = (const float*)d_in[10];
  const float* nqw = (const float*)d_in[11]; const float* nkw = (const float*)d_in[12];
  const float* Wqa = (const float*)d_in[13]; const float* bqa = (const float*)d_in[14];
  const float* Wka = (const float*)d_in[15]; const float* bka = (const float*)d_in[16];
  const float* Wva = (const float*)d_in[17]; const float* bva = (const float*)d_in[18];
  const float* naq = (const float*)d_in[19]; const float* nak = (const float*)d_in[20];
  const float* Wo  = (const float*)d_in[21]; const float* bo  = (const float*)d_in[22];
  const float* Woa = (const float*)d_in[23]; const float* boa = (const float*)d_in[24];
  const float* Wkad = (const float*)d_in[25]; const float* Wvad = (const float*)d_in[26];
  const float* bsc  = (const float*)d_in[27];
  float* out = (float*)d_out;

  char* ws = (char*)d_ws;
  u16* wt3   = (u16*)(ws);
  u16* kh    = (u16*)(ws);
  u16* vth   = (u16*)(ws + 15728640);
  u16* vdk   = (u16*)(ws + 31457280);
  u16* vdv   = (u16*)(ws + 31481856);
  u16* woaT  = (u16*)(ws + 33554432);
  u16* hbf   = (u16*)(ws + 56623104);
  u16* ebf   = (u16*)(ws + 69206016);
  u16* qh    = (u16*)(ws + 56623104);
  u16* qkvI  = (u16*)(ws + 72351744);
  u16* hsb   = (u16*)(ws + 72351744);
  u16* woT   = (u16*)(ws + 88080384);
  u16* qkvT  = (u16*)(ws + 110100480);
  float* biasA = (float*)(ws + 119537664);
  float* biasB = (float*)(ws + 119574528);

  cast2<<<3840,256,0,stream>>>(hidden, enc, hbf, 786432, 983040);
  catbias2<<<72,256,0,stream>>>(bq,bk,bv, bqa,bka,bva, biasA);
  ktrans3<<<dim3(48,48,3),256,0,stream>>>(Wq, Wk, Wv, wt3, wt3 + (size_t)DM*DM, wt3 + (size_t)2*DM*DM);
  qkv_gemm<<<dim3(16,72),256,0,stream>>>(hbf, wt3, biasA, qkvI);
  ktrans3<<<dim3(48,48,3),256,0,stream>>>(Wqa, Wka, Wva, wt3, wt3 + (size_t)DM*DM, wt3 + (size_t)2*DM*DM);
  qkv_gemm<<<dim3(4,72),256,0,stream>>>(ebf, wt3, biasB, qkvT);
  epi_fused<<<31680,256,0,stream>>>(qkvI, qkvT, nqw,nkw,naq,nak, fcos,fsin, qh, kh, vth);
  adapterk<<<6144,256,0,stream>>>(adapt, Wkad, Wvad, vdk, vdv);
  attnk<<<dim3(20,24),512,0,stream>>>(qh, kh, vth, vdk, vdv, bsc, hsb);
  ktrans3<<<dim3(48,48,2),256,0,stream>>>(Wo, Woa, Woa, woT, woaT, woaT);
  out_gemm<<<dim3(20,24),256,0,stream>>>(hsb, woT, woaT, bo, boa, out);
}

// Round 13
// 681.249 us; speedup vs baseline: 1.1178x; 1.0470x over previous
//
#include <hip/hip_runtime.h>

typedef unsigned short u16;
typedef short s16x8 __attribute__((ext_vector_type(8)));
typedef float f32x4 __attribute__((ext_vector_type(4)));

#define S_TXTC 512
#define S_TOTC 2560
#define DM 3072
#define NH 24
#define HDM 128

__device__ __forceinline__ float b2f(u16 u){ unsigned int i = ((unsigned int)u)<<16; float f; __builtin_memcpy(&f,&i,4); return f; }
__device__ __forceinline__ u16 f2b(float f){ unsigned int i; __builtin_memcpy(&i,&f,4); unsigned int r = i + 0x7FFFu + ((i>>16)&1u); return (u16)(r>>16); }
__device__ __forceinline__ s16x8 pk8(float4 a, float4 b){
  s16x8 r;
  r[0]=(short)f2b(a.x); r[1]=(short)f2b(a.y); r[2]=(short)f2b(a.z); r[3]=(short)f2b(a.w);
  r[4]=(short)f2b(b.x); r[5]=(short)f2b(b.y); r[6]=(short)f2b(b.z); r[7]=(short)f2b(b.w);
  return r;
}
__device__ __forceinline__ void g2l16(const void* g, void* l){
  __builtin_amdgcn_global_load_lds((const __attribute__((address_space(1))) void*)g,
                                   (__attribute__((address_space(3))) void*)l, 16, 0, 0);
}

__global__ __launch_bounds__(256) void fillv(float* __restrict__ p, int n, float v){
  int i = blockIdx.x*256 + threadIdx.x;
  if (i < n) p[i] = v;
}

__global__ __launch_bounds__(256) void cast2(const float* __restrict__ a, const float* __restrict__ b,
                                             u16* __restrict__ dst, int na8, int n8){
  int i = blockIdx.x*256 + threadIdx.x;
  if (i >= n8) return;
  const float* src = (i < na8)? a + (size_t)i*8 : b + (size_t)(i-na8)*8;
  float4 f0 = *(const float4*)src;
  float4 f1 = *(const float4*)(src+4);
  *(s16x8*)(dst + (size_t)i*8) = pk8(f0,f1);
}

__global__ __launch_bounds__(256) void catbias2(const float* __restrict__ b0, const float* __restrict__ b1,
    const float* __restrict__ b2, const float* __restrict__ c0, const float* __restrict__ c1,
    const float* __restrict__ c2, float* __restrict__ dst){
  int i = blockIdx.x*256 + threadIdx.x;
  if (i >= 18432) return;
  int j = (i < 9216)? i : i - 9216;
  const float* s0 = (i<9216)? b0 : c0; const float* s1 = (i<9216)? b1 : c1; const float* s2 = (i<9216)? b2 : c2;
  dst[i] = (j<3072)? s0[j] : (j<6144? s1[j-3072] : s2[j-6144]);
}

__global__ __launch_bounds__(256) void ktrans3(const float* __restrict__ W0, const float* __restrict__ W1,
    const float* __restrict__ W2, u16* __restrict__ D0, u16* __restrict__ D1, u16* __restrict__ D2){
  const float* W = (blockIdx.z==0)? W0 : ((blockIdx.z==1)? W1 : W2);
  u16* Wt = (blockIdx.z==0)? D0 : ((blockIdx.z==1)? D1 : D2);
  __shared__ __align__(16) u16 t[64*72];
  int nt = blockIdx.x*64, kt_ = blockIdx.y*64;
  int tid = threadIdx.x;
  #pragma unroll
  for (int i=0;i<2;i++){
    int q = tid + 256*i;
    int r = q>>3, c8 = (q&7)*8;
    float4 f0 = *(const float4*)(W + (size_t)(kt_+r)*DM + nt + c8);
    float4 f1 = *(const float4*)(W + (size_t)(kt_+r)*DM + nt + c8 + 4);
    *(s16x8*)&t[r*72 + c8] = pk8(f0,f1);
  }
  __syncthreads();
  #pragma unroll
  for (int i=0;i<2;i++){
    int q = tid + 256*i;
    int n = q>>3, k8 = (q&7)*8;
    s16x8 v;
    #pragma unroll
    for (int j=0;j<8;j++) v[j] = (short)t[(k8+j)*72 + n];
    *(s16x8*)(Wt + (size_t)(nt+n)*DM + kt_ + k8) = v;
  }
}

// ---------------- m97-style bf16 GEMM core ----------------
template<int OUT32>
__device__ __forceinline__ void gcore(u16* la, u16* lb,
    const u16* __restrict__ A, const u16* __restrict__ Bt,
    const float* __restrict__ bias, void* __restrict__ Cv,
    int ldc, int rb, int crb, int cb){
  const int K = DM;
  int tid = threadIdx.x, w = tid>>6, l = tid&63, g = l>>4, c16 = l&15;
  int wr = (w>>1)*64, wc = (w&1)*64;
  f32x4 acc[4][4] = {};
  const u16* aL = A  + (size_t)(rb + w*32 + (l>>2))*K + (l&3)*8;
  const u16* bL = Bt + (size_t)(cb + w*32 + (l>>2))*K + (l&3)*8;
  u16* laB = la + w*1024;
  u16* lbB = lb + w*1024;
  for (int ks=0; ks<K; ks+=32){
    g2l16(aL + ks,                laB);
    g2l16(aL + 16*(size_t)K + ks, laB + 512);
    g2l16(bL + ks,                lbB);
    g2l16(bL + 16*(size_t)K + ks, lbB + 512);
    __syncthreads();
    s16x8 af[4], bf[4];
    #pragma unroll
    for (int m=0;m<4;m++) af[m] = *(const s16x8*)&la[(wr + m*16 + c16)*32 + g*8];
    #pragma unroll
    for (int n=0;n<4;n++) bf[n] = *(const s16x8*)&lb[(wc + n*16 + c16)*32 + g*8];
    #pragma unroll
    for (int m=0;m<4;m++)
      #pragma unroll
      for (int n=0;n<4;n++)
        acc[m][n] = __builtin_amdgcn_mfma_f32_16x16x32_bf16(af[m], bf[n], acc[m][n], 0,0,0);
    __syncthreads();
  }
  #pragma unroll
  for (int n=0;n<4;n++){
    int col = cb + wc + n*16 + c16;
    float bv = bias[col];
    #pragma unroll
    for (int m=0;m<4;m++){
      int r0 = crb + wr + m*16 + g*4;
      #pragma unroll
      for (int r=0;r<4;r++){
        float oo = acc[m][n][r] + bv;
        if (OUT32) ((float*)Cv)[(size_t)(r0+r)*ldc + col] = oo;
        else       ((u16*)Cv)[(size_t)(r0+r)*ldc + col] = f2b(oo);
      }
    }
  }
}

// XCD-chunked bijective block swizzle (requires nwg % 8 == 0)
__device__ __forceinline__ void xcd_swz(int& bx, int& by){
  int gx = gridDim.x, nwg = gx*gridDim.y;
  int id = blockIdx.y*gx + blockIdx.x;
  int q = nwg>>3;
  int nid = (id&7)*q + (id>>3);
  bx = nid % gx; by = nid / gx;
}

__global__ __launch_bounds__(256) void qkv_gemm(const u16* __restrict__ A, const u16* __restrict__ Bt,
                                                const float* __restrict__ bias, u16* __restrict__ C){
  __shared__ __align__(16) u16 la[4096];
  __shared__ __align__(16) u16 lb[4096];
  int bx, by; xcd_swz(bx, by);
  gcore<0>(la, lb, A, Bt, bias, C, 3*DM, bx*128, bx*128, by*128);
}

__global__ __launch_bounds__(256) void out_gemm(const u16* __restrict__ hsb,
    const u16* __restrict__ woT, const u16* __restrict__ woaT,
    const float* __restrict__ bo, const float* __restrict__ boa, float* __restrict__ out){
  __shared__ __align__(16) u16 la[4096];
  __shared__ __align__(16) u16 lb[4096];
  int bx, by; xcd_swz(bx, by);
  bool txt = (bx < 4);
  int rb = bx*128;
  const u16* Bt = txt? woaT : woT;
  const float* bias = txt? boa : bo;
  float* dst = txt? out + (size_t)2048*DM : out;
  int crb = txt? rb : rb - 512;
  gcore<1>(la, lb, hsb, Bt, bias, dst, DM, rb, crb, by*128);
}

// ---------------- fused epilogues ----------------
__global__ __launch_bounds__(256) void epi_fused(
    const u16* __restrict__ qkvI, const u16* __restrict__ qkvT,
    const float* __restrict__ nqw, const float* __restrict__ nkw,
    const float* __restrict__ naq, const float* __restrict__ nak,
    const float* __restrict__ fcos, const float* __restrict__ fsin,
    u16* __restrict__ qh, u16* __restrict__ kh, u16* __restrict__ vt){
  __shared__ __align__(16) u16 t[64*136];
  int blk = blockIdx.x;
  if (blk < 30720){
    int wid = blk*4 + (threadIdx.x>>6);
    int lane = threadIdx.x&63;
    int which = wid / (NH*S_TOTC);
    int rem = wid % (NH*S_TOTC);
    int h = rem / S_TOTC, tok = rem % S_TOTC;
    const u16* src = ((tok<S_TXTC)? qkvT + (size_t)tok*(3*DM) : qkvI + (size_t)(tok-S_TXTC)*(3*DM))
                     + which*DM + h*HDM;
    const float* nw = which? ((tok<S_TXTC)? nak : nkw) : ((tok<S_TXTC)? naq : nqw);
    int d = lane*2;
    unsigned int u = *(const unsigned int*)(src + d);
    float x0 = b2f((u16)(u&0xffffu)), x1 = b2f((u16)(u>>16));
    float ss = x0*x0 + x1*x1;
    #pragma unroll
    for (int m=1;m<64;m<<=1) ss += __shfl_xor(ss, m);
    float rr = rsqrtf(ss*(1.f/128.f) + 1e-6f);
    float y0 = x0*rr*nw[d];
    float y1 = x1*rr*nw[d+1];
    float2 cc = *(const float2*)(fcos + (size_t)tok*HDM + d);
    float2 sn = *(const float2*)(fsin + (size_t)tok*HDM + d);
    float sc = which? 1.0f : 0.08838834764831845f;
    float o0 = (y0*cc.x - y1*sn.x)*sc;
    float o1 = (y1*cc.y + y0*sn.y)*sc;
    u16* dst = (which? kh : qh) + ((size_t)h*S_TOTC + tok)*HDM + d;
    *(unsigned int*)dst = (unsigned int)f2b(o0) | ((unsigned int)f2b(o1)<<16);
  } else {
    int bv = blk - 30720;
    int h = bv % NH, tb = bv / NH;
    int tok0 = tb*64, tid = threadIdx.x;
    #pragma unroll
    for (int i=0;i<4;i++){
      int q = tid + 256*i;
      int tr = q>>4, c8 = (q&15)*8;
      int tok = tok0 + tr;
      const u16* src = ((tok<S_TXTC)? qkvT + (size_t)tok*(3*DM) : qkvI + (size_t)(tok-S_TXTC)*(3*DM))
                       + 2*DM + h*HDM;
      *(s16x8*)&t[tr*136 + c8] = *(const s16x8*)(src + c8);
    }
    __syncthreads();
    #pragma unroll
    for (int i=0;i<4;i++){
      int q = tid + 256*i;
      int d = q>>3, j8 = (q&7)*8;
      s16x8 v;
      #pragma unroll
      for (int j=0;j<8;j++) v[j] = (short)t[(j8+j)*136 + d];
      *(s16x8*)(vt + ((size_t)h*HDM + d)*S_TOTC + tok0 + j8) = v;
    }
  }
}

__global__ __launch_bounds__(256) void adapterk(const float* __restrict__ ad, const float* __restrict__ Wk,
        const float* __restrict__ Wv, u16* __restrict__ vdk, u16* __restrict__ vdv){
  int wid = blockIdx.x*4 + (threadIdx.x>>6);
  int lane = threadIdx.x&63;
  int tensor = wid / (4*DM);
  int rem = wid % (4*DM);
  int tok = rem / DM, col = rem % DM;
  const float* Wp = tensor? Wv : Wk;
  float s = 0.f;
  #pragma unroll
  for (int i=0;i<16;i++){
    int k = lane + 64*i;
    s += ad[tok*1024 + k] * Wp[(size_t)k*DM + col];
  }
  #pragma unroll
  for (int m=1;m<64;m<<=1) s += __shfl_xor(s, m);
  if (lane==0){
    int hh = col>>7, d = col&127;
    (tensor? vdv : vdk)[(hh*4+tok)*HDM + d] = f2b(s);
  }
}

// ---------------- attn: QBLK=128, 8 waves, KVBLK=64, g2l16 double-buffer, 1 barrier/tile ----------------
__global__ __launch_bounds__(512,2) void attnk(const u16* __restrict__ qh, const u16* __restrict__ kh,
    const u16* __restrict__ vt, const u16* __restrict__ vdk, const u16* __restrict__ vdv,
    const float* __restrict__ bscale, u16* __restrict__ hs){
  __shared__ __align__(16) u16 kts[2][64*128];   // [key][d], slot ^= row&7 (via pre-swizzled source)
  __shared__ __align__(16) u16 vts[2][128*64];   // [d][key], slot ^= row&7
  __shared__ __align__(16) u16 pwb[128*64];      // [q][key], slot ^= row&7 (reg-staged)
  int h = blockIdx.y, qb = blockIdx.x*128;
  int tid = threadIdx.x, w = tid>>6, l = tid&63, g = l>>4, c16 = l&15;
  int qrow = qb + w*16 + c16;
  int c7 = c16&7;
  s16x8 qf[4];
  #pragma unroll
  for (int kc=0;kc<4;kc++) qf[kc] = *(const s16x8*)(qh + ((size_t)h*S_TOTC + qrow)*HDM + kc*32 + g*8);
  f32x4 acc[8];
  #pragma unroll
  for (int dt=0;dt<8;dt++) acc[dt] = f32x4{0.f,0.f,0.f,0.f};
  float m_[4] = {-3e38f,-3e38f,-3e38f,-3e38f};
  float l_[4] = {0.f,0.f,0.f,0.f};
  const u16* khB = kh + (size_t)h*S_TOTC*HDM;
  const u16* vtB = vt + (size_t)h*HDM*S_TOTC;

  // g2l16: LDS dest linear (wave-uniform base + lane*16); swizzle achieved by permuting GLOBAL source
  auto STAGE = [&](int buf, int kb){
    #pragma unroll
    for (int c=0;c<2;c++){
      int krow = w*8 + c*4 + (l>>4);                 // lane's LDS row
      int kchunk = (l&15) ^ (krow&7);                // pre-swizzled source chunk
      g2l16(khB + (size_t)(kb + krow)*HDM + kchunk*8, &kts[buf][w*1024 + c*512]);
      int vrow = w*16 + c*8 + (l>>3);
      int vchunk = (l&7) ^ (vrow&7);
      g2l16(vtB + (size_t)vrow*S_TOTC + kb + vchunk*8, &vts[buf][w*1024 + c*512]);
    }
  };
  auto COMPUTE = [&](int buf){
    f32x4 s[4];
    #pragma unroll
    for (int su=0;su<4;su++) s[su] = f32x4{0.f,0.f,0.f,0.f};
    __builtin_amdgcn_s_setprio(1);
    #pragma unroll
    for (int su=0;su<4;su++)
      #pragma unroll
      for (int kc=0;kc<4;kc++){
        s16x8 kf = *(const s16x8*)&kts[buf][(su*16+c16)*128 + ((kc*4+g) ^ c7)*8];
        s[su] = __builtin_amdgcn_mfma_f32_16x16x32_bf16(qf[kc], kf, s[su], 0,0,0);
      }
    __builtin_amdgcn_s_setprio(0);
    float tm[4];
    #pragma unroll
    for (int r=0;r<4;r++)
      tm[r] = fmaxf(fmaxf(s[0][r],s[1][r]), fmaxf(s[2][r],s[3][r]));
    #pragma unroll
    for (int m=1;m<16;m<<=1)
      #pragma unroll
      for (int r=0;r<4;r++) tm[r] = fmaxf(tm[r], __shfl_xor(tm[r], m));
    bool need = !__all(tm[0]<=m_[0]+8.f && tm[1]<=m_[1]+8.f && tm[2]<=m_[2]+8.f && tm[3]<=m_[3]+8.f);
    if (need){
      float corr[4];
      #pragma unroll
      for (int r=0;r<4;r++){
        float mn = fmaxf(m_[r], tm[r]);
        corr[r] = __expf(m_[r]-mn);
        m_[r] = mn;
        l_[r] *= corr[r];
      }
      #pragma unroll
      for (int dt=0;dt<8;dt++)
        #pragma unroll
        for (int r=0;r<4;r++) acc[dt][r] *= corr[r];
    }
    float rs[4];
    #pragma unroll
    for (int r=0;r<4;r++){
      rs[r] = 0.f;
      #pragma unroll
      for (int su=0;su<4;su++){ s[su][r] = __expf(s[su][r]-m_[r]); rs[r] += s[su][r]; }
    }
    #pragma unroll
    for (int m=1;m<16;m<<=1)
      #pragma unroll
      for (int r=0;r<4;r++) rs[r] += __shfl_xor(rs[r], m);
    #pragma unroll
    for (int r=0;r<4;r++) l_[r] += rs[r];
    #pragma unroll
    for (int su=0;su<4;su++){
      int kslot = su*2 + (c16>>3);
      #pragma unroll
      for (int r=0;r<4;r++){
        int prow = w*16 + g*4 + r;
        pwb[prow*64 + (kslot ^ (prow&7))*8 + c7] = f2b(s[su][r]);
      }
    }
    int prow = w*16 + c16;
    s16x8 pf0 = *(const s16x8*)&pwb[prow*64 + ((0+g) ^ c7)*8];
    s16x8 pf1 = *(const s16x8*)&pwb[prow*64 + ((4+g) ^ c7)*8];
    __builtin_amdgcn_s_setprio(1);
    #pragma unroll
    for (int dt=0;dt<8;dt++){
      int vrow = dt*16 + c16;
      s16x8 vf0 = *(const s16x8*)&vts[buf][vrow*64 + ((0+g) ^ c7)*8];
      acc[dt] = __builtin_amdgcn_mfma_f32_16x16x32_bf16(pf0, vf0, acc[dt], 0,0,0);
      s16x8 vf1 = *(const s16x8*)&vts[buf][vrow*64 + ((4+g) ^ c7)*8];
      acc[dt] = __builtin_amdgcn_mfma_f32_16x16x32_bf16(pf1, vf1, acc[dt], 0,0,0);
    }
    __builtin_amdgcn_s_setprio(0);
  };

  STAGE(0, 0);
  __syncthreads();
  int cur = 0;
  for (int kb=0; kb<S_TOTC; kb+=64){
    if (kb+64 < S_TOTC) STAGE(cur^1, kb+64);   // prefetch flies under compute
    COMPUTE(cur);
    __syncthreads();                            // drains vmcnt (loads landed) + syncs readers
    cur ^= 1;
  }

  // adapter cross-attention: stage 4 K rows / 4 V keys into buffer 0 (swizzled), stale rest masked by P=0
  if (tid < 64){
    int row = tid>>4, slot = (tid&15) ^ (row&7);
    *(s16x8*)&kts[0][row*128 + slot*8] = *(const s16x8*)(vdk + (h*4+(tid>>4))*HDM + (tid&15)*8);
  } else if (tid < 192){
    int d = tid - 64;
    int sl0 = (d&7)*8;
    #pragma unroll
    for (int key=0;key<4;key++) vts[0][d*64 + sl0 + key] = vdv[(h*4+key)*HDM + d];
  }
  __syncthreads();
  f32x4 s2 = {0.f,0.f,0.f,0.f};
  #pragma unroll
  for (int kc=0;kc<4;kc++){
    s16x8 kf = *(const s16x8*)&kts[0][c16*128 + ((kc*4+g) ^ c7)*8];
    s2 = __builtin_amdgcn_mfma_f32_16x16x32_bf16(qf[kc], kf, s2, 0,0,0);
  }
  bool valid = (c16 < 4);
  float m2[4], l2[4];
  #pragma unroll
  for (int r=0;r<4;r++) m2[r] = valid? s2[r] : -3e38f;
  #pragma unroll
  for (int m=1;m<16;m<<=1)
    #pragma unroll
    for (int r=0;r<4;r++) m2[r] = fmaxf(m2[r], __shfl_xor(m2[r], m));
  #pragma unroll
  for (int r=0;r<4;r++){ float p = valid? __expf(s2[r]-m2[r]) : 0.f; s2[r]=p; l2[r]=p; }
  #pragma unroll
  for (int m=1;m<16;m<<=1)
    #pragma unroll
    for (int r=0;r<4;r++) l2[r] += __shfl_xor(l2[r], m);
  #pragma unroll
  for (int r=0;r<4;r++){
    int prow = w*16 + g*4 + r;
    int s0 = (c16>>3) ^ (prow&7);
    int s1 = (2 + (c16>>3)) ^ (prow&7);
    pwb[prow*64 + s0*8 + c7] = f2b(s2[r]);
    pwb[prow*64 + s1*8 + c7] = (u16)0;
  }
  int prow2 = w*16 + c16;
  s16x8 pf2 = *(const s16x8*)&pwb[prow2*64 + (g ^ c7)*8];
  f32x4 a2[8];
  #pragma unroll
  for (int dt=0;dt<8;dt++) a2[dt] = f32x4{0.f,0.f,0.f,0.f};
  #pragma unroll
  for (int dt=0;dt<8;dt++){
    int vrow = dt*16 + c16;
    s16x8 vf = *(const s16x8*)&vts[0][vrow*64 + (g ^ c7)*8];
    a2[dt] = __builtin_amdgcn_mfma_f32_16x16x32_bf16(pf2, vf, a2[dt], 0,0,0);
  }
  float sb = bscale[0];
  float rl[4], rl2[4];
  #pragma unroll
  for (int r=0;r<4;r++){ rl[r] = 1.f/l_[r]; rl2[r] = sb/l2[r]; }
  #pragma unroll
  for (int dt=0;dt<8;dt++)
    #pragma unroll
    for (int r=0;r<4;r++){
      int tok = qb + w*16 + g*4 + r;
      int col = h*HDM + dt*16 + c16;
      hs[(size_t)tok*DM + col] = f2b(acc[dt][r]*rl[r] + a2[dt][r]*rl2[r]);
    }
}

extern "C" void kernel_launch(void* const* d_in, const int* in_sizes, int n_in,
                              void* d_out, int out_size, void* d_ws, size_t ws_size,
                              hipStream_t stream){
  static const int expect[28] = {
    6291456, 1572864, 4096, 327680, 327680,
    9437184, 3072, 9437184, 3072, 9437184, 3072, 128, 128,
    9437184, 3072, 9437184, 3072, 9437184, 3072, 128, 128,
    9437184, 3072, 9437184, 3072, 3145728, 3145728, 1 };
  bool ok = (n_in == 28);
  if (ok) for (int i=0;i<28;i++) if (in_sizes[i] != expect[i]) { ok = false; break; }
  if (!ok){ fillv<<<(out_size+255)/256,256,0,stream>>>((float*)d_out, out_size, 7.0f); return; }
  if (ws_size < 119611392ull){ fillv<<<(out_size+255)/256,256,0,stream>>>((float*)d_out, out_size, 9.0f); return; }

  const float* hidden = (const float*)d_in[0];
  const float* enc    = (const float*)d_in[1];
  const float* adapt  = (const float*)d_in[2];
  const float* fcos   = (const float*)d_in[3];
  const float* fsin   = (const float*)d_in[4];
  const float* Wq  = (const float*)d_in[5];  const float* bq  = (const float*)d_in[6];
  const float* Wk  = (const float*)d_in[7];  const float* bk  = (const float*)d_in[8];
  const float* Wv  = (const float*)d_in[9];  const float* bv  = (const float*)d_in[10];
  const float* nqw = (const float*)d_in[11]; const float* nkw = (const float*)d_in[12];
  const float* Wqa = (const float*)d_in[13]; const float* bqa = (const float*)d_in[14];
  const float* Wka = (const float*)d_in[15]; const float* bka = (const float*)d_in[16];
  const float* Wva = (const float*)d_in[17]; const float* bva = (const float*)d_in[18];
  const float* naq = (const float*)d_in[19]; const float* nak = (const float*)d_in[20];
  const float* Wo  = (const float*)d_in[21]; const float* bo  = (const float*)d_in[22];
  const float* Woa = (const float*)d_in[23]; const float* boa = (const float*)d_in[24];
  const float* Wkad = (const float*)d_in[25]; const float* Wvad = (const float*)d_in[26];
  const float* bsc  = (const float*)d_in[27];
  float* out = (float*)d_out;

  char* ws = (char*)d_ws;
  u16* wt3   = (u16*)(ws);
  u16* kh    = (u16*)(ws);
  u16* vth   = (u16*)(ws + 15728640);
  u16* vdk   = (u16*)(ws + 31457280);
  u16* vdv   = (u16*)(ws + 31481856);
  u16* woaT  = (u16*)(ws + 33554432);
  u16* hbf   = (u16*)(ws + 56623104);
  u16* ebf   = (u16*)(ws + 69206016);
  u16* qh    = (u16*)(ws + 56623104);
  u16* qkvI  = (u16*)(ws + 72351744);
  u16* hsb   = (u16*)(ws + 72351744);
  u16* woT   = (u16*)(ws + 88080384);
  u16* qkvT  = (u16*)(ws + 110100480);
  float* biasA = (float*)(ws + 119537664);
  float* biasB = (float*)(ws + 119574528);

  cast2<<<3840,256,0,stream>>>(hidden, enc, hbf, 786432, 983040);
  catbias2<<<72,256,0,stream>>>(bq,bk,bv, bqa,bka,bva, biasA);
  ktrans3<<<dim3(48,48,3),256,0,stream>>>(Wq, Wk, Wv, wt3, wt3 + (size_t)DM*DM, wt3 + (size_t)2*DM*DM);
  qkv_gemm<<<dim3(16,72),256,0,stream>>>(hbf, wt3, biasA, qkvI);
  ktrans3<<<dim3(48,48,3),256,0,stream>>>(Wqa, Wka, Wva, wt3, wt3 + (size_t)DM*DM, wt3 + (size_t)2*DM*DM);
  qkv_gemm<<<dim3(4,72),256,0,stream>>>(ebf, wt3, biasB, qkvT);
  epi_fused<<<31680,256,0,stream>>>(qkvI, qkvT, nqw,nkw,naq,nak, fcos,fsin, qh, kh, vth);
  adapterk<<<6144,256,0,stream>>>(adapt, Wkad, Wvad, vdk, vdv);
  attnk<<<dim3(20,24),512,0,stream>>>(qh, kh, vth, vdk, vdv, bsc, hsb);
  ktrans3<<<dim3(48,48,2),256,0,stream>>>(Wo, Woa, Woa, woT, woaT, woaT);
  out_gemm<<<dim3(20,24),256,0,stream>>>(hsb, woT, woaT, bo, boa, out);
}